// Round 6
// baseline (1877.376 us; speedup 1.0000x reference)
//
#include <hip/hip_runtime.h>
#include <hip/hip_fp16.h>
#include <stdint.h>

#define BB 8
#define NN 4096
#define ATTRD 16
#define HD 64
#define STEPS 8
#define NODES (BB*NN)      // 32768
#define ECAP 96            // nnz/row ~ Poisson(41); P(>=96) astronomically small

typedef unsigned long long ull;

// ---------------- init: h = relu(attr @ Wi^T + bi); fp32 master + fp16 mirror ----------------
__global__ void init_h_kernel(const float* __restrict__ attr, const float* __restrict__ Wi,
                              const float* __restrict__ bi, float* __restrict__ h,
                              __half* __restrict__ h16) {
    int idx = blockIdx.x * blockDim.x + threadIdx.x;   // node*64 + l
    if (idx >= NODES * HD) return;
    int node = idx >> 6, l = idx & 63;
    const float* a = attr + node * ATTRD;
    const float* w = Wi + l * ATTRD;
    float acc = bi[l];
#pragma unroll
    for (int k = 0; k < ATTRD; k++) acc += a[k] * w[k];
    float r = acc > 0.f ? acc : 0.f;
    h[idx] = r;
    h16[idx] = __float2half(r);
}

// ---------------- weight transpose prep (k-tiled float4 layout, fp32) ----------------
// wzrT4[(k/4)*128 + o] (float4 over k%4), rows 0..63 = Wz, 64..127 = Wr
// whT4 [(k/4)*64  + o] (float4 over k%4)
__global__ void wprep_kernel(const float* __restrict__ Wz, const float* __restrict__ Wr,
                             const float* __restrict__ Wh,
                             float* __restrict__ wzrT4, float* __restrict__ whT4) {
    int t = blockIdx.x * blockDim.x + threadIdx.x;
    if (t < 128 * 192) {
        int o = t / 192, k = t % 192;
        float v = (o < 64) ? Wz[o * 192 + k] : Wr[(o - 64) * 192 + k];
        wzrT4[((k >> 2) * 128 + o) * 4 + (k & 3)] = v;
    } else if (t < 128 * 192 + 64 * 192) {
        int t2 = t - 128 * 192;
        int o = t2 / 192, k = t2 % 192;
        whT4[((k >> 2) * 64 + o) * 4 + (k & 3)] = Wh[o * 192 + k];
    }
}

// ---------------- single-pass ELL build, 4 loads in flight ----------------
__device__ __forceinline__ void cf_process(float4 v, int e, ull mask_lt, int l,
                                           int* cnt_in, int* cnt_out,
                                           int* edge_in, int* edge_out) {
    int row = e >> 12;                                 // wave-uniform
    ull b0 = __ballot(v.x != 0.f);
    ull b1 = __ballot(v.y != 0.f);
    ull b2 = __ballot(v.z != 0.f);
    ull b3 = __ballot(v.w != 0.f);
    int total = __popcll(b0) + __popcll(b1) + __popcll(b2) + __popcll(b3);
    int base = 0;
    if (l == 0 && total) base = atomicAdd(&cnt_in[row], total);
    base = __shfl(base, 0);
    if (total) {
        int pre = __popcll(b0 & mask_lt) + __popcll(b1 & mask_lt) +
                  __popcll(b2 & mask_lt) + __popcll(b3 & mask_lt);
        float vv[4] = {v.x, v.y, v.z, v.w};
        int inner = 0;
        int colbase = (e >> 24) << 12;
#pragma unroll
        for (int c = 0; c < 4; c++) {
            if (vv[c] != 0.f) {
                int col = colbase | ((e + c) & 4095);
                int s1 = base + pre + inner;
                if (s1 < ECAP) edge_in[row * ECAP + s1] = col;
                inner++;
                int s2 = atomicAdd(&cnt_out[col], 1);
                if (s2 < ECAP) edge_out[col * ECAP + s2] = row;
            }
        }
    }
}

__global__ void count_fill_kernel(const float4* __restrict__ A4,
                                  int* __restrict__ cnt_in, int* __restrict__ cnt_out,
                                  int* __restrict__ edge_in, int* __restrict__ edge_out) {
    // grid fixed 8192x256: stride = 2097152; total4 = 33554432 = 16 * stride exactly.
    int tid0 = blockIdx.x * blockDim.x + threadIdx.x;
    const int stride = gridDim.x * blockDim.x;
    int l = threadIdx.x & 63;
    ull mask_lt = (l == 63) ? ~0ull >> 1 : ((1ull << (l + 1)) - 1) >> 1; // bits < l
#pragma unroll 1
    for (int o = 0; o < 4; o++) {
        int i0 = tid0 + (o * 4 + 0) * stride;
        int i1 = tid0 + (o * 4 + 1) * stride;
        int i2 = tid0 + (o * 4 + 2) * stride;
        int i3 = tid0 + (o * 4 + 3) * stride;
        float4 v0 = A4[i0];
        float4 v1 = A4[i1];
        float4 v2 = A4[i2];
        float4 v3 = A4[i3];
        cf_process(v0, i0 * 4, mask_lt, l, cnt_in, cnt_out, edge_in, edge_out);
        cf_process(v1, i1 * 4, mask_lt, l, cnt_in, cnt_out, edge_in, edge_out);
        cf_process(v2, i2 * 4, mask_lt, l, cnt_in, cnt_out, edge_in, edge_out);
        cf_process(v3, i3 * 4, mask_lt, l, cnt_in, cnt_out, edge_in, edge_out);
    }
}

// ---------------- fused GGNN step: gather -> LDS xs (fp32) -> fp32 VALU gates -> h_next ------
// Block: 256 threads (4 waves), 16 nodes. Grid 2048, XCD swizzle (bid&7 = batch).
// Double-buffered h: reads h_cur/h16_cur, writes h_nxt/h16_nxt.
// Wave w owns nodes w*4..w*4+3 in BOTH the gather and gate phases.
__global__ __launch_bounds__(256) void step_kernel(
        const __half2* __restrict__ h2g, const float* __restrict__ hg,
        const int* __restrict__ cnt_in, const int* __restrict__ edge_in,
        const int* __restrict__ cnt_out, const int* __restrict__ edge_out,
        const float* __restrict__ wzrT4, const float* __restrict__ whT4,
        const float* __restrict__ bz, const float* __restrict__ br,
        const float* __restrict__ bh,
        float* __restrict__ h_out, __half* __restrict__ h16_out) {
    __shared__ float xs_t[16 * 192];     // 12 KB, row stride 192 floats (as round-4 gate_kernel)
    __shared__ float h32[16][64];        // 4 KB fp32 h for epilogue

    int bid = blockIdx.x;
    int batch = bid & 7, grp = bid >> 3;              // batch -> XCD locality
    int node_base = (batch << 12) + grp * 16;
    int tid = threadIdx.x;
    int wave = tid >> 6, lane = tid & 63;

    // ---- stage h: fp32 -> h32 LDS and xs slot 128.. (256 float4s = 16 nodes x 16) ----
    {
        const float4* hsrc = (const float4*)(hg + ((size_t)node_base << 6));
        int nl = tid >> 4, c4 = (tid & 15) * 4;
        float4 g = hsrc[tid];
        h32[nl][c4 + 0] = g.x; h32[nl][c4 + 1] = g.y;
        h32[nl][c4 + 2] = g.z; h32[nl][c4 + 3] = g.w;
        *(float4*)(xs_t + nl * 192 + 128 + c4) = g;
    }

    // ---- phase A: gather. wave w handles (node,dir) tasks for nodes w*4..w*4+3. ----
    int half = lane >> 5, sl = lane & 31;
    for (int t = 0; t < 8; t++) {
        int tt = wave * 8 + t;
        int nl = tt >> 1, dir = tt & 1;
        int node = node_base + nl;
        int n = dir ? cnt_out[node] : cnt_in[node];
        if (n > ECAP) n = ECAP;
        const int* eidx = (dir ? edge_out : edge_in) + node * ECAP;
        float a0 = 0.f, a1 = 0.f;
        int s = 0;
        for (; s + 8 <= n; s += 8) {                  // 4 gathers in flight per half-wave
            int i0 = eidx[s + 0 + half];
            int i1 = eidx[s + 2 + half];
            int i2 = eidx[s + 4 + half];
            int i3 = eidx[s + 6 + half];
            float2 f0 = __half22float2(h2g[(i0 << 5) | sl]);
            float2 f1 = __half22float2(h2g[(i1 << 5) | sl]);
            float2 f2 = __half22float2(h2g[(i2 << 5) | sl]);
            float2 f3 = __half22float2(h2g[(i3 << 5) | sl]);
            a0 += f0.x; a1 += f0.y;
            a0 += f1.x; a1 += f1.y;
            a0 += f2.x; a1 += f2.y;
            a0 += f3.x; a1 += f3.y;
        }
        for (; s + 2 <= n; s += 2) {
            float2 f0 = __half22float2(h2g[(eidx[s + half] << 5) | sl]);
            a0 += f0.x; a1 += f0.y;
        }
        if (s < n && half == 0) {
            float2 f0 = __half22float2(h2g[(eidx[s] << 5) | sl]);
            a0 += f0.x; a1 += f0.y;
        }
        a0 += __shfl_xor(a0, 32);
        a1 += __shfl_xor(a1, 32);
        if (half == 0) {
            float2 st = {a0, a1};
            *(float2*)(xs_t + nl * 192 + dir * 64 + 2 * sl) = st;
        }
    }
    __syncthreads();

    // ---- phase B: z,r (fp32 VALU, round-4-proven). Wave w: nodes w*4..w*4+3, lane = out ch. ----
    int w = wave, l = lane;
    const float4* Wzr4 = (const float4*)wzrT4;
    float az[4] = {0.f, 0.f, 0.f, 0.f};
    float ar[4] = {0.f, 0.f, 0.f, 0.f};
#pragma unroll 4
    for (int kg = 0; kg < 48; ++kg) {
        float4 wz = Wzr4[kg * 128 + l];
        float4 wr = Wzr4[kg * 128 + 64 + l];
#pragma unroll
        for (int n = 0; n < 4; n++) {
            float4 x = *(const float4*)(xs_t + (w * 4 + n) * 192 + kg * 4);
            az[n] += wz.x * x.x + wz.y * x.y + wz.z * x.z + wz.w * x.w;
            ar[n] += wr.x * x.x + wr.y * x.y + wr.z * x.z + wr.w * x.w;
        }
    }
    float bzv = bz[l], brv = br[l], bhv = bh[l];
    float z[4], hv[4];
#pragma unroll
    for (int n = 0; n < 4; n++) {
        z[n] = 1.f / (1.f + __expf(-(az[n] + bzv)));
        float r = 1.f / (1.f + __expf(-(ar[n] + brv)));
        hv[n] = h32[w * 4 + n][l];
        ar[n] = r * hv[n];                            // stash r*h
    }
    __syncthreads();                                  // all reads of slot 128+ complete
#pragma unroll
    for (int n = 0; n < 4; n++) xs_t[(w * 4 + n) * 192 + 128 + l] = ar[n];
    __syncthreads();

    // ---- phase C: hn = tanh([inp, r*h] @ Wh^T + bh); h' = h + z*(hn - h) ----
    const float4* Wh4 = (const float4*)whT4;
    float ah[4] = {0.f, 0.f, 0.f, 0.f};
#pragma unroll 4
    for (int kg = 0; kg < 48; ++kg) {
        float4 wv = Wh4[kg * 64 + l];
#pragma unroll
        for (int n = 0; n < 4; n++) {
            float4 x = *(const float4*)(xs_t + (w * 4 + n) * 192 + kg * 4);
            ah[n] += wv.x * x.x + wv.y * x.y + wv.z * x.z + wv.w * x.w;
        }
    }
#pragma unroll
    for (int n = 0; n < 4; n++) {
        float pre = ah[n] + bhv;
        float th = 2.f / (1.f + __expf(-2.f * pre)) - 1.f;   // tanh
        float hn = hv[n] + z[n] * (th - hv[n]);
        int gi = ((node_base + w * 4 + n) << 6) | l;
        h_out[gi] = hn;
        h16_out[gi] = __float2half(hn);
    }
}

// ---------------- output: out = h @ Wo^T + bo ----------------
__global__ void out_kernel(const float* __restrict__ h, const float* __restrict__ Wo,
                           const float* __restrict__ bo, float* __restrict__ out) {
    int wid = (blockIdx.x * blockDim.x + threadIdx.x) >> 6;
    int l = threadIdx.x & 63;
    if (wid >= NODES) return;
    float p = h[(wid << 6) | l] * Wo[l];
#pragma unroll
    for (int off = 32; off > 0; off >>= 1) p += __shfl_down(p, off);
    if (l == 0) out[wid] = p + bo[0];
}

extern "C" void kernel_launch(void* const* d_in, const int* in_sizes, int n_in,
                              void* d_out, int out_size, void* d_ws, size_t ws_size,
                              hipStream_t stream) {
    const float* attr = (const float*)d_in[0];
    const float* adj  = (const float*)d_in[1];
    const float* Wi   = (const float*)d_in[2];
    const float* bi   = (const float*)d_in[3];
    const float* Wz   = (const float*)d_in[4];
    const float* bz   = (const float*)d_in[5];
    const float* Wr   = (const float*)d_in[6];
    const float* br   = (const float*)d_in[7];
    const float* Wh   = (const float*)d_in[8];
    const float* bh   = (const float*)d_in[9];
    const float* Wo   = (const float*)d_in[10];
    const float* bo   = (const float*)d_in[11];
    float* out = (float*)d_out;

    // workspace carve (256B-aligned), total ~51 MB
    char* ws = (char*)d_ws;
    size_t off = 0;
    auto carve = [&](size_t bytes) { void* p = ws + off; off = (off + bytes + 255) & ~(size_t)255; return p; };
    float*  hA    = (float*)carve((size_t)NODES * HD * 4);        // 8.4 MB
    float*  hB    = (float*)carve((size_t)NODES * HD * 4);        // 8.4 MB
    __half* hA16  = (__half*)carve((size_t)NODES * HD * 2);       // 4.2 MB
    __half* hB16  = (__half*)carve((size_t)NODES * HD * 2);       // 4.2 MB
    float* wzrT4  = (float*)carve(192 * 128 * 4);
    float* whT4   = (float*)carve(192 * 64 * 4);
    int* cnt_in   = (int*)carve((size_t)2 * NODES * 4);
    int* cnt_out  = cnt_in + NODES;
    int* edge_in  = (int*)carve((size_t)NODES * ECAP * 4);        // 12.6 MB
    int* edge_out = (int*)carve((size_t)NODES * ECAP * 4);        // 12.6 MB

    hipMemsetAsync(cnt_in, 0, (size_t)2 * NODES * 4, stream);

    init_h_kernel<<<NODES * HD / 256, 256, 0, stream>>>(attr, Wi, bi, hA, hA16);
    wprep_kernel<<<(128 * 192 + 64 * 192 + 255) / 256, 256, 0, stream>>>(Wz, Wr, Wh, wzrT4, whT4);
    count_fill_kernel<<<8192, 256, 0, stream>>>((const float4*)adj, cnt_in, cnt_out,
                                                edge_in, edge_out);

    const float* hc = hA; const __half* hc16 = hA16;
    float* hx = hB; __half* hx16 = hB16;
    for (int step = 0; step < STEPS; ++step) {
        step_kernel<<<NODES / 16, 256, 0, stream>>>(
            (const __half2*)hc16, hc, cnt_in, edge_in, cnt_out, edge_out,
            wzrT4, whT4, bz, br, bh, hx, hx16);
        const float* tf = hc; hc = hx; hx = (float*)tf;
        const __half* th = hc16; hc16 = hx16; hx16 = (__half*)th;
    }
    out_kernel<<<NODES * HD / 256, 256, 0, stream>>>(hc, Wo, bo, out);
}

// Round 7
// 1597.255 us; speedup vs baseline: 1.1754x; 1.1754x over previous
//
#include <hip/hip_runtime.h>
#include <hip/hip_fp16.h>
#include <stdint.h>

#define BB 8
#define NN 4096
#define ATTRD 16
#define HD 64
#define STEPS 8
#define NODES (BB*NN)      // 32768
#define ECAP 96            // nnz/row ~ Poisson(41); P(>=96) astronomically small

typedef unsigned long long ull;

// ---------------- init: h = relu(attr @ Wi^T + bi); fp32 master + fp16 mirror ----------------
__global__ void init_h_kernel(const float* __restrict__ attr, const float* __restrict__ Wi,
                              const float* __restrict__ bi, float* __restrict__ h,
                              __half* __restrict__ h16) {
    int idx = blockIdx.x * blockDim.x + threadIdx.x;   // node*64 + l
    if (idx >= NODES * HD) return;
    int node = idx >> 6, l = idx & 63;
    const float* a = attr + node * ATTRD;
    const float* w = Wi + l * ATTRD;
    float acc = bi[l];
#pragma unroll
    for (int k = 0; k < ATTRD; k++) acc += a[k] * w[k];
    float r = acc > 0.f ? acc : 0.f;
    h[idx] = r;
    h16[idx] = __float2half(r);
}

// ---------------- weight transpose prep (k-tiled float4 layout, fp32) ----------------
__global__ void wprep_kernel(const float* __restrict__ Wz, const float* __restrict__ Wr,
                             const float* __restrict__ Wh,
                             float* __restrict__ wzrT4, float* __restrict__ whT4) {
    int t = blockIdx.x * blockDim.x + threadIdx.x;
    if (t < 128 * 192) {
        int o = t / 192, k = t % 192;
        float v = (o < 64) ? Wz[o * 192 + k] : Wr[(o - 64) * 192 + k];
        wzrT4[((k >> 2) * 128 + o) * 4 + (k & 3)] = v;
    } else if (t < 128 * 192 + 64 * 192) {
        int t2 = t - 128 * 192;
        int o = t2 / 192, k = t2 % 192;
        whT4[((k >> 2) * 64 + o) * 4 + (k & 3)] = Wh[o * 192 + k];
    }
}

// ---------------- single-pass ELL build, batched latency chains ----------------
// 4 tiles (256 elems each) per outer iter: all loads, then all ballots, then ONE
// atomic instruction (lanes 0..3 reserve rows for tiles 0..3), then shfls, then stores.
__global__ void count_fill_kernel(const float4* __restrict__ A4,
                                  int* __restrict__ cnt_in, int* __restrict__ cnt_out,
                                  int* __restrict__ edge_in, int* __restrict__ edge_out) {
    // grid fixed 8192x256: stride = 2097152; total4 = 33554432 = 16 * stride exactly.
    int tid0 = blockIdx.x * blockDim.x + threadIdx.x;
    const int stride = gridDim.x * blockDim.x;
    int l = threadIdx.x & 63;
    ull mask_lt = (l == 63) ? ~0ull >> 1 : ((1ull << (l + 1)) - 1) >> 1; // bits < l
#pragma unroll 1
    for (int o = 0; o < 4; o++) {
        int idx[4]; float4 v[4];
#pragma unroll
        for (int c = 0; c < 4; c++) idx[c] = tid0 + (o * 4 + c) * stride;
#pragma unroll
        for (int c = 0; c < 4; c++) v[c] = A4[idx[c]];       // 4 loads in flight
        ull b[4][4]; int tot[4]; int row[4];
#pragma unroll
        for (int c = 0; c < 4; c++) {
            b[c][0] = __ballot(v[c].x != 0.f);
            b[c][1] = __ballot(v[c].y != 0.f);
            b[c][2] = __ballot(v[c].z != 0.f);
            b[c][3] = __ballot(v[c].w != 0.f);
            tot[c] = __popcll(b[c][0]) + __popcll(b[c][1]) +
                     __popcll(b[c][2]) + __popcll(b[c][3]);
            row[c] = idx[c] >> 10;                            // (idx*4)>>12, wave-uniform
        }
        // one atomic instruction: lane c (c<4) reserves tile c's row slots
        int myTot = (l == 1) ? tot[1] : (l == 2) ? tot[2] : (l == 3) ? tot[3] : tot[0];
        int myRow = (l == 1) ? row[1] : (l == 2) ? row[2] : (l == 3) ? row[3] : row[0];
        int res = 0;
        if (l < 4 && myTot) res = atomicAdd(&cnt_in[myRow], myTot);
        int base[4];
#pragma unroll
        for (int c = 0; c < 4; c++) base[c] = __shfl(res, c);
        // in-edge stores (slots deterministic: base + ballot-prefix + component order)
#pragma unroll
        for (int c = 0; c < 4; c++) {
            if (!tot[c]) continue;                            // wave-uniform skip
            int e = idx[c] * 4;
            int colbase = (e >> 24) << 12;
            int pre = __popcll(b[c][0] & mask_lt) + __popcll(b[c][1] & mask_lt) +
                      __popcll(b[c][2] & mask_lt) + __popcll(b[c][3] & mask_lt);
            float vv[4] = {v[c].x, v[c].y, v[c].z, v[c].w};
            int inner = 0;
#pragma unroll
            for (int q = 0; q < 4; q++) {
                if (vv[q] != 0.f) {
                    int s1 = base[c] + pre + inner;
                    if (s1 < ECAP) edge_in[row[c] * ECAP + s1] = colbase | ((e + q) & 4095);
                    inner++;
                }
            }
        }
        // out-edge atomics + stores (per-lane, ~uncontended: 256 distinct cols per tile)
#pragma unroll
        for (int c = 0; c < 4; c++) {
            if (!tot[c]) continue;
            int e = idx[c] * 4;
            int colbase = (e >> 24) << 12;
            float vv[4] = {v[c].x, v[c].y, v[c].z, v[c].w};
#pragma unroll
            for (int q = 0; q < 4; q++) {
                if (vv[q] != 0.f) {
                    int col = colbase | ((e + q) & 4095);
                    int s2 = atomicAdd(&cnt_out[col], 1);
                    if (s2 < ECAP) edge_out[col * ECAP + s2] = row[c];
                }
            }
        }
    }
}

// ---------------- aggregation: xs = [A@h | A^T@h | h] ----------------
// One wave per (node,dir) — 65536 waves, 8x CU oversubscription for latency hiding.
// Half-wave (32 lanes) covers one fp16 row (128 B) as __half2 loads; 8 loads in flight.
// XCD swizzle: blockIdx % 8 == batch.
__global__ __launch_bounds__(256) void aggregate_kernel(
        const __half2* __restrict__ h2, const float* __restrict__ h,
        const int* __restrict__ cnt_in, const int* __restrict__ edge_in,
        const int* __restrict__ cnt_out, const int* __restrict__ edge_out,
        float* __restrict__ xs) {
    int bid = blockIdx.x;
    int batch = bid & 7;
    int group = bid >> 3;                      // 0..2047
    int wave = threadIdx.x >> 6;
    int pair = group * 4 + wave;               // 0..8191 within batch
    int node = (batch << 12) + (pair >> 1);
    int dir = pair & 1;
    int l = threadIdx.x & 63;
    int half = l >> 5;                         // which edge of a pair
    int sl = l & 31;                           // channel-pair index
    int n = dir ? cnt_out[node] : cnt_in[node];
    if (n > ECAP) n = ECAP;
    const int* eidx = (dir ? edge_out : edge_in) + node * ECAP;
    float a0 = 0.f, a1 = 0.f;                  // channels 2*sl, 2*sl+1
    int s = 0;
    for (; s + 16 <= n; s += 16) {             // 16 edges/iter: 8 loads in flight per half-wave
        int i0 = eidx[s +  0 + half];
        int i1 = eidx[s +  2 + half];
        int i2 = eidx[s +  4 + half];
        int i3 = eidx[s +  6 + half];
        int i4 = eidx[s +  8 + half];
        int i5 = eidx[s + 10 + half];
        int i6 = eidx[s + 12 + half];
        int i7 = eidx[s + 14 + half];
        float2 f0 = __half22float2(h2[(i0 << 5) | sl]);
        float2 f1 = __half22float2(h2[(i1 << 5) | sl]);
        float2 f2 = __half22float2(h2[(i2 << 5) | sl]);
        float2 f3 = __half22float2(h2[(i3 << 5) | sl]);
        float2 f4 = __half22float2(h2[(i4 << 5) | sl]);
        float2 f5 = __half22float2(h2[(i5 << 5) | sl]);
        float2 f6 = __half22float2(h2[(i6 << 5) | sl]);
        float2 f7 = __half22float2(h2[(i7 << 5) | sl]);
        a0 += f0.x; a1 += f0.y;  a0 += f1.x; a1 += f1.y;
        a0 += f2.x; a1 += f2.y;  a0 += f3.x; a1 += f3.y;
        a0 += f4.x; a1 += f4.y;  a0 += f5.x; a1 += f5.y;
        a0 += f6.x; a1 += f6.y;  a0 += f7.x; a1 += f7.y;
    }
    for (; s + 8 <= n; s += 8) {
        int i0 = eidx[s + 0 + half];
        int i1 = eidx[s + 2 + half];
        int i2 = eidx[s + 4 + half];
        int i3 = eidx[s + 6 + half];
        float2 f0 = __half22float2(h2[(i0 << 5) | sl]);
        float2 f1 = __half22float2(h2[(i1 << 5) | sl]);
        float2 f2 = __half22float2(h2[(i2 << 5) | sl]);
        float2 f3 = __half22float2(h2[(i3 << 5) | sl]);
        a0 += f0.x; a1 += f0.y;  a0 += f1.x; a1 += f1.y;
        a0 += f2.x; a1 += f2.y;  a0 += f3.x; a1 += f3.y;
    }
    for (; s + 2 <= n; s += 2) {
        float2 f0 = __half22float2(h2[(eidx[s + half] << 5) | sl]);
        a0 += f0.x; a1 += f0.y;
    }
    if (s < n && half == 0) {                  // odd leftover edge -> half 0 only
        float2 f0 = __half22float2(h2[(eidx[s] << 5) | sl]);
        a0 += f0.x; a1 += f0.y;
    }
    a0 += __shfl_xor(a0, 32);
    a1 += __shfl_xor(a1, 32);
    if (half == 0) {
        float2 st = {a0, a1};
        *(float2*)(xs + node * 192 + dir * 64 + sl * 2) = st;
    }
    if (dir == 0) xs[node * 192 + 128 + l] = h[(node << 6) | l];  // fp32 master h slot
}

// ---------------- fused gates: z,r = sig(xs@W^T+b); hn = tanh([inp,r*h]@Wh^T+bh); h += z*(hn-h) ----
// XCD-swizzled to match aggregate so each XCD reads the xs it wrote (3.1 MB/XCD, L2-resident).
__global__ __launch_bounds__(256) void gate_kernel(const float* __restrict__ xs_g,
                                                   const float* __restrict__ wzrT4,
                                                   const float* __restrict__ whT4,
                                                   const float* __restrict__ bz,
                                                   const float* __restrict__ br,
                                                   const float* __restrict__ bh,
                                                   float* __restrict__ h,
                                                   __half* __restrict__ h16) {
    __shared__ float xs_t[16 * 192];    // 12 KB
    int bid = blockIdx.x;
    int base = ((bid & 7) << 12) | ((bid >> 3) << 4);   // batch-major node base
    int tid = threadIdx.x;
    const float4* src = (const float4*)(xs_g + base * 192);
    float4* dst = (float4*)xs_t;
#pragma unroll
    for (int i = 0; i < 3; i++) dst[tid + i * 256] = src[tid + i * 256];
    __syncthreads();
    int w = tid >> 6, l = tid & 63;
    const float4* Wzr4 = (const float4*)wzrT4;
    float az[4] = {0.f, 0.f, 0.f, 0.f};
    float ar[4] = {0.f, 0.f, 0.f, 0.f};
#pragma unroll 4
    for (int kg = 0; kg < 48; ++kg) {
        float4 wz = Wzr4[kg * 128 + l];
        float4 wr = Wzr4[kg * 128 + 64 + l];
#pragma unroll
        for (int n = 0; n < 4; n++) {
            float4 x = *(const float4*)(xs_t + (w * 4 + n) * 192 + kg * 4);
            az[n] += wz.x * x.x + wz.y * x.y + wz.z * x.z + wz.w * x.w;
            ar[n] += wr.x * x.x + wr.y * x.y + wr.z * x.z + wr.w * x.w;
        }
    }
    float bzv = bz[l], brv = br[l], bhv = bh[l];
    float z[4], hv[4];
#pragma unroll
    for (int n = 0; n < 4; n++) {
        z[n] = 1.f / (1.f + __expf(-(az[n] + bzv)));
        float r = 1.f / (1.f + __expf(-(ar[n] + brv)));
        hv[n] = xs_t[(w * 4 + n) * 192 + 128 + l];
        ar[n] = r * hv[n];                     // stash r*h
    }
    __syncthreads();                           // all reads of slot h done
#pragma unroll
    for (int n = 0; n < 4; n++) xs_t[(w * 4 + n) * 192 + 128 + l] = ar[n];
    __syncthreads();
    const float4* Wh4 = (const float4*)whT4;
    float ah[4] = {0.f, 0.f, 0.f, 0.f};
#pragma unroll 4
    for (int kg = 0; kg < 48; ++kg) {
        float4 wv = Wh4[kg * 64 + l];
#pragma unroll
        for (int n = 0; n < 4; n++) {
            float4 x = *(const float4*)(xs_t + (w * 4 + n) * 192 + kg * 4);
            ah[n] += wv.x * x.x + wv.y * x.y + wv.z * x.z + wv.w * x.w;
        }
    }
#pragma unroll
    for (int n = 0; n < 4; n++) {
        int gi = ((base + w * 4 + n) << 6) | l;
        float pre = ah[n] + bhv;
        float th = 2.f / (1.f + __expf(-2.f * pre)) - 1.f;   // tanh
        float hn = hv[n] + z[n] * (th - hv[n]);
        h[gi] = hn;
        h16[gi] = __float2half(hn);
    }
}

// ---------------- output: out = h @ Wo^T + bo ----------------
__global__ void out_kernel(const float* __restrict__ h, const float* __restrict__ Wo,
                           const float* __restrict__ bo, float* __restrict__ out) {
    int wid = (blockIdx.x * blockDim.x + threadIdx.x) >> 6;
    int l = threadIdx.x & 63;
    if (wid >= NODES) return;
    float p = h[(wid << 6) | l] * Wo[l];
#pragma unroll
    for (int off = 32; off > 0; off >>= 1) p += __shfl_down(p, off);
    if (l == 0) out[wid] = p + bo[0];
}

extern "C" void kernel_launch(void* const* d_in, const int* in_sizes, int n_in,
                              void* d_out, int out_size, void* d_ws, size_t ws_size,
                              hipStream_t stream) {
    const float* attr = (const float*)d_in[0];
    const float* adj  = (const float*)d_in[1];
    const float* Wi   = (const float*)d_in[2];
    const float* bi   = (const float*)d_in[3];
    const float* Wz   = (const float*)d_in[4];
    const float* bz   = (const float*)d_in[5];
    const float* Wr   = (const float*)d_in[6];
    const float* br   = (const float*)d_in[7];
    const float* Wh   = (const float*)d_in[8];
    const float* bh   = (const float*)d_in[9];
    const float* Wo   = (const float*)d_in[10];
    const float* bo   = (const float*)d_in[11];
    float* out = (float*)d_out;

    // workspace carve (256B-aligned), total ~64 MB
    char* ws = (char*)d_ws;
    size_t off = 0;
    auto carve = [&](size_t bytes) { void* p = ws + off; off = (off + bytes + 255) & ~(size_t)255; return p; };
    float* h      = (float*)carve((size_t)NODES * HD * 4);        // 8.4 MB
    __half* h16   = (__half*)carve((size_t)NODES * HD * 2);       // 4.2 MB
    float* xs     = (float*)carve((size_t)NODES * 192 * 4);       // 25.2 MB
    float* wzrT4  = (float*)carve(192 * 128 * 4);
    float* whT4   = (float*)carve(192 * 64 * 4);
    int* cnt_in   = (int*)carve((size_t)2 * NODES * 4);           // cnt_in + cnt_out contiguous
    int* cnt_out  = cnt_in + NODES;
    int* edge_in  = (int*)carve((size_t)NODES * ECAP * 4);        // 12.6 MB
    int* edge_out = (int*)carve((size_t)NODES * ECAP * 4);        // 12.6 MB

    hipMemsetAsync(cnt_in, 0, (size_t)2 * NODES * 4, stream);

    init_h_kernel<<<NODES * HD / 256, 256, 0, stream>>>(attr, Wi, bi, h, h16);
    wprep_kernel<<<(128 * 192 + 64 * 192 + 255) / 256, 256, 0, stream>>>(Wz, Wr, Wh, wzrT4, whT4);
    count_fill_kernel<<<8192, 256, 0, stream>>>((const float4*)adj, cnt_in, cnt_out,
                                                edge_in, edge_out);

    for (int step = 0; step < STEPS; ++step) {
        aggregate_kernel<<<NODES * 2 * 64 / 256, 256, 0, stream>>>(
            (const __half2*)h16, h, cnt_in, edge_in, cnt_out, edge_out, xs);
        gate_kernel<<<NODES / 16, 256, 0, stream>>>(xs, wzrT4, whT4, bz, br, bh, h, h16);
    }
    out_kernel<<<NODES * HD / 256, 256, 0, stream>>>(h, Wo, bo, out);
}

// Round 8
// 1258.806 us; speedup vs baseline: 1.4914x; 1.2689x over previous
//
#include <hip/hip_runtime.h>
#include <hip/hip_fp16.h>
#include <stdint.h>

#define BB 8
#define NN 4096
#define ATTRD 16
#define HD 64
#define STEPS 8
#define NODES (BB*NN)      // 32768
#define ECAP 96            // nnz/row ~ Poisson(41); P(>=96) astronomically small
#define KPAD 196           // xs_t row stride in floats (784 B = 49*16, breaks pow2 banks)

typedef _Float16 half8 __attribute__((ext_vector_type(8)));
typedef float floatx4 __attribute__((ext_vector_type(4)));
typedef unsigned long long ull;

// ---------------- init: h = relu(attr @ Wi^T + bi); fp32 master + fp16 mirror ----------------
__global__ void init_h_kernel(const float* __restrict__ attr, const float* __restrict__ Wi,
                              const float* __restrict__ bi, float* __restrict__ h,
                              __half* __restrict__ h16) {
    int idx = blockIdx.x * blockDim.x + threadIdx.x;   // node*64 + l
    if (idx >= NODES * HD) return;
    int node = idx >> 6, l = idx & 63;
    const float* a = attr + node * ATTRD;
    const float* w = Wi + l * ATTRD;
    float acc = bi[l];
#pragma unroll
    for (int k = 0; k < ATTRD; k++) acc += a[k] * w[k];
    float r = acc > 0.f ? acc : 0.f;
    h[idx] = r;
    h16[idx] = __float2half(r);
}

// ---------------- weight prep: split-fp16 MFMA B-fragments ----------------
// wf[mat(0=z,1=r,2=h)][tile(4)][kc(6)][lane(64)][j(8)]; value = W[och][k],
// och = tile*16 + (lane&15), k = kc*32 + (lane>>4)*8 + j.  hi = fp16(v), lo = fp16(v - hi).
__global__ void wprep_kernel(const float* __restrict__ Wz, const float* __restrict__ Wr,
                             const float* __restrict__ Wh,
                             _Float16* __restrict__ wf_hi, _Float16* __restrict__ wf_lo) {
    int t = blockIdx.x * blockDim.x + threadIdx.x;
    if (t >= 3 * 4 * 6 * 64 * 8) return;
    int mat = t / 12288, rem = t % 12288;
    int tile = rem / 3072, rem2 = rem % 3072;
    int kc = rem2 / 512, rem3 = rem2 % 512;
    int lane = rem3 / 8, j = rem3 % 8;
    int k = kc * 32 + (lane >> 4) * 8 + j;
    int och = tile * 16 + (lane & 15);
    const float* W = (mat == 0) ? Wz : (mat == 1) ? Wr : Wh;
    float v = W[och * 192 + k];
    _Float16 hi = (_Float16)v;
    wf_hi[t] = hi;
    wf_lo[t] = (_Float16)(v - (float)hi);
}

// ---------------- single-pass ELL build, batched latency chains (r7-proven) ----------------
__global__ void count_fill_kernel(const float4* __restrict__ A4,
                                  int* __restrict__ cnt_in, int* __restrict__ cnt_out,
                                  int* __restrict__ edge_in, int* __restrict__ edge_out) {
    int tid0 = blockIdx.x * blockDim.x + threadIdx.x;
    const int stride = gridDim.x * blockDim.x;
    int l = threadIdx.x & 63;
    ull mask_lt = (l == 63) ? ~0ull >> 1 : ((1ull << (l + 1)) - 1) >> 1; // bits < l
#pragma unroll 1
    for (int o = 0; o < 4; o++) {
        int idx[4]; float4 v[4];
#pragma unroll
        for (int c = 0; c < 4; c++) idx[c] = tid0 + (o * 4 + c) * stride;
#pragma unroll
        for (int c = 0; c < 4; c++) v[c] = A4[idx[c]];
        ull b[4][4]; int tot[4]; int row[4];
#pragma unroll
        for (int c = 0; c < 4; c++) {
            b[c][0] = __ballot(v[c].x != 0.f);
            b[c][1] = __ballot(v[c].y != 0.f);
            b[c][2] = __ballot(v[c].z != 0.f);
            b[c][3] = __ballot(v[c].w != 0.f);
            tot[c] = __popcll(b[c][0]) + __popcll(b[c][1]) +
                     __popcll(b[c][2]) + __popcll(b[c][3]);
            row[c] = idx[c] >> 10;
        }
        int myTot = (l == 1) ? tot[1] : (l == 2) ? tot[2] : (l == 3) ? tot[3] : tot[0];
        int myRow = (l == 1) ? row[1] : (l == 2) ? row[2] : (l == 3) ? row[3] : row[0];
        int res = 0;
        if (l < 4 && myTot) res = atomicAdd(&cnt_in[myRow], myTot);
        int base[4];
#pragma unroll
        for (int c = 0; c < 4; c++) base[c] = __shfl(res, c);
#pragma unroll
        for (int c = 0; c < 4; c++) {
            if (!tot[c]) continue;
            int e = idx[c] * 4;
            int colbase = (e >> 24) << 12;
            int pre = __popcll(b[c][0] & mask_lt) + __popcll(b[c][1] & mask_lt) +
                      __popcll(b[c][2] & mask_lt) + __popcll(b[c][3] & mask_lt);
            float vv[4] = {v[c].x, v[c].y, v[c].z, v[c].w};
            int inner = 0;
#pragma unroll
            for (int q = 0; q < 4; q++) {
                if (vv[q] != 0.f) {
                    int s1 = base[c] + pre + inner;
                    if (s1 < ECAP) edge_in[row[c] * ECAP + s1] = colbase | ((e + q) & 4095);
                    inner++;
                }
            }
        }
#pragma unroll
        for (int c = 0; c < 4; c++) {
            if (!tot[c]) continue;
            int e = idx[c] * 4;
            int colbase = (e >> 24) << 12;
            float vv[4] = {v[c].x, v[c].y, v[c].z, v[c].w};
#pragma unroll
            for (int q = 0; q < 4; q++) {
                if (vv[q] != 0.f) {
                    int col = colbase | ((e + q) & 4095);
                    int s2 = atomicAdd(&cnt_out[col], 1);
                    if (s2 < ECAP) edge_out[col * ECAP + s2] = row[c];
                }
            }
        }
    }
}

// ---------------- aggregation: xs = [A@h | A^T@h | h] (r7-proven) ----------------
__global__ __launch_bounds__(256) void aggregate_kernel(
        const __half2* __restrict__ h2, const float* __restrict__ h,
        const int* __restrict__ cnt_in, const int* __restrict__ edge_in,
        const int* __restrict__ cnt_out, const int* __restrict__ edge_out,
        float* __restrict__ xs) {
    int bid = blockIdx.x;
    int batch = bid & 7;
    int group = bid >> 3;
    int wave = threadIdx.x >> 6;
    int pair = group * 4 + wave;
    int node = (batch << 12) + (pair >> 1);
    int dir = pair & 1;
    int l = threadIdx.x & 63;
    int half = l >> 5, sl = l & 31;
    int n = dir ? cnt_out[node] : cnt_in[node];
    if (n > ECAP) n = ECAP;
    const int* eidx = (dir ? edge_out : edge_in) + node * ECAP;
    float a0 = 0.f, a1 = 0.f;
    int s = 0;
    for (; s + 16 <= n; s += 16) {
        int i0 = eidx[s +  0 + half];
        int i1 = eidx[s +  2 + half];
        int i2 = eidx[s +  4 + half];
        int i3 = eidx[s +  6 + half];
        int i4 = eidx[s +  8 + half];
        int i5 = eidx[s + 10 + half];
        int i6 = eidx[s + 12 + half];
        int i7 = eidx[s + 14 + half];
        float2 f0 = __half22float2(h2[(i0 << 5) | sl]);
        float2 f1 = __half22float2(h2[(i1 << 5) | sl]);
        float2 f2 = __half22float2(h2[(i2 << 5) | sl]);
        float2 f3 = __half22float2(h2[(i3 << 5) | sl]);
        float2 f4 = __half22float2(h2[(i4 << 5) | sl]);
        float2 f5 = __half22float2(h2[(i5 << 5) | sl]);
        float2 f6 = __half22float2(h2[(i6 << 5) | sl]);
        float2 f7 = __half22float2(h2[(i7 << 5) | sl]);
        a0 += f0.x; a1 += f0.y;  a0 += f1.x; a1 += f1.y;
        a0 += f2.x; a1 += f2.y;  a0 += f3.x; a1 += f3.y;
        a0 += f4.x; a1 += f4.y;  a0 += f5.x; a1 += f5.y;
        a0 += f6.x; a1 += f6.y;  a0 += f7.x; a1 += f7.y;
    }
    for (; s + 8 <= n; s += 8) {
        int i0 = eidx[s + 0 + half];
        int i1 = eidx[s + 2 + half];
        int i2 = eidx[s + 4 + half];
        int i3 = eidx[s + 6 + half];
        float2 f0 = __half22float2(h2[(i0 << 5) | sl]);
        float2 f1 = __half22float2(h2[(i1 << 5) | sl]);
        float2 f2 = __half22float2(h2[(i2 << 5) | sl]);
        float2 f3 = __half22float2(h2[(i3 << 5) | sl]);
        a0 += f0.x; a1 += f0.y;  a0 += f1.x; a1 += f1.y;
        a0 += f2.x; a1 += f2.y;  a0 += f3.x; a1 += f3.y;
    }
    for (; s + 2 <= n; s += 2) {
        float2 f0 = __half22float2(h2[(eidx[s + half] << 5) | sl]);
        a0 += f0.x; a1 += f0.y;
    }
    if (s < n && half == 0) {
        float2 f0 = __half22float2(h2[(eidx[s] << 5) | sl]);
        a0 += f0.x; a1 += f0.y;
    }
    a0 += __shfl_xor(a0, 32);
    a1 += __shfl_xor(a1, 32);
    if (half == 0) {
        float2 st = {a0, a1};
        *(float2*)(xs + node * 192 + dir * 64 + sl * 2) = st;
    }
    if (dir == 0) xs[node * 192 + 128 + l] = h[(node << 6) | l];
}

// ---------------- gates via split-fp16 MFMA (fp32-accurate): ----------------
// z,r = sig(xs@W^T+b); hn = tanh([inp,r*h]@Wh^T+bh); h' = h + z*(hn-h).
// A = Ahi + Alo (fp16 split of fp32 xs in LDS); W = Whi + Wlo (prepacked).
// acc = Ahi*Whi + Alo*Whi + Ahi*Wlo  (lo*lo dropped, ~5e-7/term).
__global__ __launch_bounds__(256) void gate_kernel(
        const float* __restrict__ xs_g,
        const _Float16* __restrict__ wf_hi, const _Float16* __restrict__ wf_lo,
        const float* __restrict__ bz, const float* __restrict__ br,
        const float* __restrict__ bh,
        float* __restrict__ h, __half* __restrict__ h16) {
    __shared__ float xs_t[16][KPAD];     // 12.5 KB
    int bid = blockIdx.x;
    int base = ((bid & 7) << 12) | ((bid >> 3) << 4);   // XCD-swizzled node base
    int tid = threadIdx.x;
    {
        const float4* src = (const float4*)(xs_g + base * 192);
#pragma unroll
        for (int i = 0; i < 3; i++) {
            int idx = tid + i * 256;          // 768 float4s = 16 nodes x 48
            float4 v = src[idx];
            int nl = idx / 48, kb = (idx % 48) * 4;
            *(float4*)&xs_t[nl][kb] = v;
        }
    }
    __syncthreads();
    int wave = tid >> 6, lane = tid & 63;
    int m = lane & 15, q = lane >> 4;
    int ch = wave * 16 + m;                   // global output channel (C/D col=lane&15)
    const half8* WH = (const half8*)wf_hi;
    const half8* WL = (const half8*)wf_lo;

    floatx4 accz = {0.f, 0.f, 0.f, 0.f};
    floatx4 accr = {0.f, 0.f, 0.f, 0.f};
#pragma unroll
    for (int kc = 0; kc < 6; kc++) {
        const float* xr = &xs_t[m][kc * 32 + q * 8];
        float4 xa = *(const float4*)xr;
        float4 xb = *(const float4*)(xr + 4);
        float xv[8] = {xa.x, xa.y, xa.z, xa.w, xb.x, xb.y, xb.z, xb.w};
        half8 ahi, alo;
#pragma unroll
        for (int j = 0; j < 8; j++) {
            _Float16 hj = (_Float16)xv[j];
            ahi[j] = hj;
            alo[j] = (_Float16)(xv[j] - (float)hj);
        }
        half8 bzh = WH[((0 * 4 + wave) * 6 + kc) * 64 + lane];
        half8 bzl = WL[((0 * 4 + wave) * 6 + kc) * 64 + lane];
        half8 brh = WH[((1 * 4 + wave) * 6 + kc) * 64 + lane];
        half8 brl = WL[((1 * 4 + wave) * 6 + kc) * 64 + lane];
        accz = __builtin_amdgcn_mfma_f32_16x16x32_f16(ahi, bzh, accz, 0, 0, 0);
        accz = __builtin_amdgcn_mfma_f32_16x16x32_f16(alo, bzh, accz, 0, 0, 0);
        accz = __builtin_amdgcn_mfma_f32_16x16x32_f16(ahi, bzl, accz, 0, 0, 0);
        accr = __builtin_amdgcn_mfma_f32_16x16x32_f16(ahi, brh, accr, 0, 0, 0);
        accr = __builtin_amdgcn_mfma_f32_16x16x32_f16(alo, brh, accr, 0, 0, 0);
        accr = __builtin_amdgcn_mfma_f32_16x16x32_f16(ahi, brl, accr, 0, 0, 0);
    }
    float bzv = bz[ch], brv = br[ch], bhv = bh[ch];
    float zreg[4], hvreg[4], rh[4];
#pragma unroll
    for (int rg = 0; rg < 4; rg++) {
        int nl = q * 4 + rg;                  // C/D row=(lane>>4)*4+reg -> node
        float z = 1.f / (1.f + __expf(-(accz[rg] + bzv)));
        float r = 1.f / (1.f + __expf(-(accr[rg] + brv)));
        float hv = xs_t[nl][128 + ch];
        zreg[rg] = z; hvreg[rg] = hv; rh[rg] = r * hv;
    }
    __syncthreads();                          // all zr A-frag reads of slots 128+ done
#pragma unroll
    for (int rg = 0; rg < 4; rg++) xs_t[q * 4 + rg][128 + ch] = rh[rg];
    __syncthreads();

    floatx4 acch = {0.f, 0.f, 0.f, 0.f};
#pragma unroll
    for (int kc = 0; kc < 6; kc++) {
        const float* xr = &xs_t[m][kc * 32 + q * 8];
        float4 xa = *(const float4*)xr;
        float4 xb = *(const float4*)(xr + 4);
        float xv[8] = {xa.x, xa.y, xa.z, xa.w, xb.x, xb.y, xb.z, xb.w};
        half8 ahi, alo;
#pragma unroll
        for (int j = 0; j < 8; j++) {
            _Float16 hj = (_Float16)xv[j];
            ahi[j] = hj;
            alo[j] = (_Float16)(xv[j] - (float)hj);
        }
        half8 bhh = WH[((2 * 4 + wave) * 6 + kc) * 64 + lane];
        half8 bhl = WL[((2 * 4 + wave) * 6 + kc) * 64 + lane];
        acch = __builtin_amdgcn_mfma_f32_16x16x32_f16(ahi, bhh, acch, 0, 0, 0);
        acch = __builtin_amdgcn_mfma_f32_16x16x32_f16(alo, bhh, acch, 0, 0, 0);
        acch = __builtin_amdgcn_mfma_f32_16x16x32_f16(ahi, bhl, acch, 0, 0, 0);
    }
    __syncthreads();                          // all hn A-frag reads done before overwrite
#pragma unroll
    for (int rg = 0; rg < 4; rg++) {
        int nl = q * 4 + rg;
        float pre = acch[rg] + bhv;
        float th = 2.f / (1.f + __expf(-2.f * pre)) - 1.f;
        float hv = hvreg[rg];
        xs_t[nl][ch] = hv + zreg[rg] * (th - hv);   // stage h' for coalesced write
    }
    __syncthreads();
    {
        int f = tid * 4;                      // 1024 floats = 16 nodes x 64
        int nl = f >> 6, c = f & 63;
        float4 v = *(const float4*)&xs_t[nl][c];
        int gi = ((base + nl) << 6) | c;
        *(float4*)&h[gi] = v;
        __half2 p0 = {__float2half(v.x), __float2half(v.y)};
        __half2 p1 = {__float2half(v.z), __float2half(v.w)};
        *(__half2*)&h16[gi] = p0;
        *(__half2*)&h16[gi + 2] = p1;
    }
}

// ---------------- output: out = h @ Wo^T + bo ----------------
__global__ void out_kernel(const float* __restrict__ h, const float* __restrict__ Wo,
                           const float* __restrict__ bo, float* __restrict__ out) {
    int wid = (blockIdx.x * blockDim.x + threadIdx.x) >> 6;
    int l = threadIdx.x & 63;
    if (wid >= NODES) return;
    float p = h[(wid << 6) | l] * Wo[l];
#pragma unroll
    for (int off = 32; off > 0; off >>= 1) p += __shfl_down(p, off);
    if (l == 0) out[wid] = p + bo[0];
}

extern "C" void kernel_launch(void* const* d_in, const int* in_sizes, int n_in,
                              void* d_out, int out_size, void* d_ws, size_t ws_size,
                              hipStream_t stream) {
    const float* attr = (const float*)d_in[0];
    const float* adj  = (const float*)d_in[1];
    const float* Wi   = (const float*)d_in[2];
    const float* bi   = (const float*)d_in[3];
    const float* Wz   = (const float*)d_in[4];
    const float* bz   = (const float*)d_in[5];
    const float* Wr   = (const float*)d_in[6];
    const float* br   = (const float*)d_in[7];
    const float* Wh   = (const float*)d_in[8];
    const float* bh   = (const float*)d_in[9];
    const float* Wo   = (const float*)d_in[10];
    const float* bo   = (const float*)d_in[11];
    float* out = (float*)d_out;

    char* ws = (char*)d_ws;
    size_t off = 0;
    auto carve = [&](size_t bytes) { void* p = ws + off; off = (off + bytes + 255) & ~(size_t)255; return p; };
    float* h      = (float*)carve((size_t)NODES * HD * 4);        // 8.4 MB
    __half* h16   = (__half*)carve((size_t)NODES * HD * 2);       // 4.2 MB
    float* xs     = (float*)carve((size_t)NODES * 192 * 4);       // 25.2 MB
    _Float16* wf_hi = (_Float16*)carve(3 * 4 * 6 * 64 * 8 * 2);   // 73.7 KB
    _Float16* wf_lo = (_Float16*)carve(3 * 4 * 6 * 64 * 8 * 2);   // 73.7 KB
    int* cnt_in   = (int*)carve((size_t)2 * NODES * 4);
    int* cnt_out  = cnt_in + NODES;
    int* edge_in  = (int*)carve((size_t)NODES * ECAP * 4);        // 12.6 MB
    int* edge_out = (int*)carve((size_t)NODES * ECAP * 4);        // 12.6 MB

    hipMemsetAsync(cnt_in, 0, (size_t)2 * NODES * 4, stream);

    init_h_kernel<<<NODES * HD / 256, 256, 0, stream>>>(attr, Wi, bi, h, h16);
    wprep_kernel<<<(3 * 4 * 6 * 64 * 8 + 255) / 256, 256, 0, stream>>>(Wz, Wr, Wh, wf_hi, wf_lo);
    count_fill_kernel<<<8192, 256, 0, stream>>>((const float4*)adj, cnt_in, cnt_out,
                                                edge_in, edge_out);

    for (int step = 0; step < STEPS; ++step) {
        aggregate_kernel<<<NODES * 2 * 64 / 256, 256, 0, stream>>>(
            (const __half2*)h16, h, cnt_in, edge_in, cnt_out, edge_out, xs);
        gate_kernel<<<NODES / 16, 256, 0, stream>>>(xs, wf_hi, wf_lo, bz, br, bh, h, h16);
    }
    out_kernel<<<NODES * HD / 256, 256, 0, stream>>>(h, Wo, bo, out);
}

// Round 9
// 1255.227 us; speedup vs baseline: 1.4956x; 1.0029x over previous
//
#include <hip/hip_runtime.h>
#include <hip/hip_fp16.h>
#include <stdint.h>

#define BB 8
#define NN 4096
#define ATTRD 16
#define HD 64
#define STEPS 8
#define NODES (BB*NN)      // 32768
#define ECAP 96            // nnz/row ~ Poisson(41); P(>=96) astronomically small
#define KPAD 196           // xs_t row stride in floats

typedef _Float16 half8 __attribute__((ext_vector_type(8)));
typedef float floatx4 __attribute__((ext_vector_type(4)));
typedef unsigned long long ull;

// ---------------- init: h = relu(attr @ Wi^T + bi); fp32 master + fp16 mirror ----------------
__global__ void init_h_kernel(const float* __restrict__ attr, const float* __restrict__ Wi,
                              const float* __restrict__ bi, float* __restrict__ h,
                              __half* __restrict__ h16) {
    int idx = blockIdx.x * blockDim.x + threadIdx.x;   // node*64 + l
    if (idx >= NODES * HD) return;
    int node = idx >> 6, l = idx & 63;
    const float* a = attr + node * ATTRD;
    const float* w = Wi + l * ATTRD;
    float acc = bi[l];
#pragma unroll
    for (int k = 0; k < ATTRD; k++) acc += a[k] * w[k];
    float r = acc > 0.f ? acc : 0.f;
    h[idx] = r;
    h16[idx] = __float2half(r);
}

// ---------------- weight prep: split-fp16 MFMA B-fragments (r8-proven) ----------------
__global__ void wprep_kernel(const float* __restrict__ Wz, const float* __restrict__ Wr,
                             const float* __restrict__ Wh,
                             _Float16* __restrict__ wf_hi, _Float16* __restrict__ wf_lo) {
    int t = blockIdx.x * blockDim.x + threadIdx.x;
    if (t >= 3 * 4 * 6 * 64 * 8) return;
    int mat = t / 12288, rem = t % 12288;
    int tile = rem / 3072, rem2 = rem % 3072;
    int kc = rem2 / 512, rem3 = rem2 % 512;
    int lane = rem3 / 8, j = rem3 % 8;
    int k = kc * 32 + (lane >> 4) * 8 + j;
    int och = tile * 16 + (lane & 15);
    const float* W = (mat == 0) ? Wz : (mat == 1) ? Wr : Wh;
    float v = W[och * 192 + k];
    _Float16 hi = (_Float16)v;
    wf_hi[t] = hi;
    wf_lo[t] = (_Float16)(v - (float)hi);
}

// ---------------- in-edge ELL build: one wave per adjacency row, ATOMIC-FREE ----------------
// Row = 4096 elems = 1024 float4 = 64 lanes x 16. All 16 loads in flight; slots from
// wave-local lex-rank prefix (ballot). cnt_in written directly (no memset needed).
__global__ __launch_bounds__(256) void count_rows_kernel(const float4* __restrict__ A4,
                                                         int* __restrict__ cnt_in,
                                                         int* __restrict__ edge_in) {
    int wave = threadIdx.x >> 6, l = threadIdx.x & 63;
    int row = blockIdx.x * 4 + wave;                   // 0..32767
    const float4* rp = A4 + (size_t)row * 1024;
    ull mask_lt = (l == 63) ? ~0ull >> 1 : ((1ull << (l + 1)) - 1) >> 1; // bits < l
    float4 v[16];
#pragma unroll
    for (int t = 0; t < 16; t++) v[t] = rp[t * 64 + l];   // 16 coalesced 1KB loads in flight
    int colbase = (row >> 12) << 12;                      // batch * 4096
    int run = 0;
    int* erow = edge_in + row * ECAP;
#pragma unroll
    for (int t = 0; t < 16; t++) {
        ull b0 = __ballot(v[t].x != 0.f);
        ull b1 = __ballot(v[t].y != 0.f);
        ull b2 = __ballot(v[t].z != 0.f);
        ull b3 = __ballot(v[t].w != 0.f);
        int pre = __popcll(b0 & mask_lt) + __popcll(b1 & mask_lt) +
                  __popcll(b2 & mask_lt) + __popcll(b3 & mask_lt);
        float vv[4] = {v[t].x, v[t].y, v[t].z, v[t].w};
        int jbase = (t * 64 + l) * 4;                     // elem index within row: 0..4092
        int inner = 0;
#pragma unroll
        for (int q = 0; q < 4; q++) {
            if (vv[q] != 0.f) {
                int slot = run + pre + inner;             // lex rank (l-major, q-minor) ✓injective
                if (slot < ECAP) erow[slot] = colbase | (jbase + q);
                inner++;
            }
        }
        run += __popcll(b0) + __popcll(b1) + __popcll(b2) + __popcll(b3);
    }
    if (l == 0) cnt_in[row] = run;
}

// ---------------- out-edge build: transpose the ELL (reads 5.4 MB, not 537 MB) ----------------
// One wave per row; lanes process distinct cols of that row -> 64 independent atomic chains.
__global__ __launch_bounds__(256) void transpose_kernel(const int* __restrict__ cnt_in,
                                                        const int* __restrict__ edge_in,
                                                        int* __restrict__ cnt_out,
                                                        int* __restrict__ edge_out) {
    int wave = threadIdx.x >> 6, l = threadIdx.x & 63;
    int row = blockIdx.x * 4 + wave;
    int n = cnt_in[row]; if (n > ECAP) n = ECAP;
    for (int s = l; s < n; s += 64) {
        int j = edge_in[row * ECAP + s];
        int s2 = atomicAdd(&cnt_out[j], 1);
        if (s2 < ECAP) edge_out[j * ECAP + s2] = row;
    }
}

// ---------------- aggregation: xs = [A@h | A^T@h | h] (r7/r8-proven) ----------------
__global__ __launch_bounds__(256) void aggregate_kernel(
        const __half2* __restrict__ h2, const float* __restrict__ h,
        const int* __restrict__ cnt_in, const int* __restrict__ edge_in,
        const int* __restrict__ cnt_out, const int* __restrict__ edge_out,
        float* __restrict__ xs) {
    int bid = blockIdx.x;
    int batch = bid & 7;
    int group = bid >> 3;
    int wave = threadIdx.x >> 6;
    int pair = group * 4 + wave;
    int node = (batch << 12) + (pair >> 1);
    int dir = pair & 1;
    int l = threadIdx.x & 63;
    int half = l >> 5, sl = l & 31;
    int n = dir ? cnt_out[node] : cnt_in[node];
    if (n > ECAP) n = ECAP;
    const int* eidx = (dir ? edge_out : edge_in) + node * ECAP;
    float a0 = 0.f, a1 = 0.f;
    int s = 0;
    for (; s + 16 <= n; s += 16) {
        int i0 = eidx[s +  0 + half];
        int i1 = eidx[s +  2 + half];
        int i2 = eidx[s +  4 + half];
        int i3 = eidx[s +  6 + half];
        int i4 = eidx[s +  8 + half];
        int i5 = eidx[s + 10 + half];
        int i6 = eidx[s + 12 + half];
        int i7 = eidx[s + 14 + half];
        float2 f0 = __half22float2(h2[(i0 << 5) | sl]);
        float2 f1 = __half22float2(h2[(i1 << 5) | sl]);
        float2 f2 = __half22float2(h2[(i2 << 5) | sl]);
        float2 f3 = __half22float2(h2[(i3 << 5) | sl]);
        float2 f4 = __half22float2(h2[(i4 << 5) | sl]);
        float2 f5 = __half22float2(h2[(i5 << 5) | sl]);
        float2 f6 = __half22float2(h2[(i6 << 5) | sl]);
        float2 f7 = __half22float2(h2[(i7 << 5) | sl]);
        a0 += f0.x; a1 += f0.y;  a0 += f1.x; a1 += f1.y;
        a0 += f2.x; a1 += f2.y;  a0 += f3.x; a1 += f3.y;
        a0 += f4.x; a1 += f4.y;  a0 += f5.x; a1 += f5.y;
        a0 += f6.x; a1 += f6.y;  a0 += f7.x; a1 += f7.y;
    }
    for (; s + 8 <= n; s += 8) {
        int i0 = eidx[s + 0 + half];
        int i1 = eidx[s + 2 + half];
        int i2 = eidx[s + 4 + half];
        int i3 = eidx[s + 6 + half];
        float2 f0 = __half22float2(h2[(i0 << 5) | sl]);
        float2 f1 = __half22float2(h2[(i1 << 5) | sl]);
        float2 f2 = __half22float2(h2[(i2 << 5) | sl]);
        float2 f3 = __half22float2(h2[(i3 << 5) | sl]);
        a0 += f0.x; a1 += f0.y;  a0 += f1.x; a1 += f1.y;
        a0 += f2.x; a1 += f2.y;  a0 += f3.x; a1 += f3.y;
    }
    for (; s + 2 <= n; s += 2) {
        float2 f0 = __half22float2(h2[(eidx[s + half] << 5) | sl]);
        a0 += f0.x; a1 += f0.y;
    }
    if (s < n && half == 0) {
        float2 f0 = __half22float2(h2[(eidx[s] << 5) | sl]);
        a0 += f0.x; a1 += f0.y;
    }
    a0 += __shfl_xor(a0, 32);
    a1 += __shfl_xor(a1, 32);
    if (half == 0) {
        float2 st = {a0, a1};
        *(float2*)(xs + node * 192 + dir * 64 + sl * 2) = st;
    }
    if (dir == 0) xs[node * 192 + 128 + l] = h[(node << 6) | l];
}

// ---------------- gates via split-fp16 MFMA (r8-proven, fp32-accurate) ----------------
__global__ __launch_bounds__(256) void gate_kernel(
        const float* __restrict__ xs_g,
        const _Float16* __restrict__ wf_hi, const _Float16* __restrict__ wf_lo,
        const float* __restrict__ bz, const float* __restrict__ br,
        const float* __restrict__ bh,
        float* __restrict__ h, __half* __restrict__ h16) {
    __shared__ float xs_t[16][KPAD];     // 12.5 KB
    int bid = blockIdx.x;
    int base = ((bid & 7) << 12) | ((bid >> 3) << 4);   // XCD-swizzled node base
    int tid = threadIdx.x;
    {
        const float4* src = (const float4*)(xs_g + base * 192);
#pragma unroll
        for (int i = 0; i < 3; i++) {
            int idx = tid + i * 256;          // 768 float4s = 16 nodes x 48
            float4 v = src[idx];
            int nl = idx / 48, kb = (idx % 48) * 4;
            *(float4*)&xs_t[nl][kb] = v;
        }
    }
    __syncthreads();
    int wave = tid >> 6, lane = tid & 63;
    int m = lane & 15, q = lane >> 4;
    int ch = wave * 16 + m;                   // global output channel (C/D col=lane&15)
    const half8* WH = (const half8*)wf_hi;
    const half8* WL = (const half8*)wf_lo;

    floatx4 accz = {0.f, 0.f, 0.f, 0.f};
    floatx4 accr = {0.f, 0.f, 0.f, 0.f};
#pragma unroll
    for (int kc = 0; kc < 6; kc++) {
        const float* xr = &xs_t[m][kc * 32 + q * 8];
        float4 xa = *(const float4*)xr;
        float4 xb = *(const float4*)(xr + 4);
        float xv[8] = {xa.x, xa.y, xa.z, xa.w, xb.x, xb.y, xb.z, xb.w};
        half8 ahi, alo;
#pragma unroll
        for (int j = 0; j < 8; j++) {
            _Float16 hj = (_Float16)xv[j];
            ahi[j] = hj;
            alo[j] = (_Float16)(xv[j] - (float)hj);
        }
        half8 bzh = WH[((0 * 4 + wave) * 6 + kc) * 64 + lane];
        half8 bzl = WL[((0 * 4 + wave) * 6 + kc) * 64 + lane];
        half8 brh = WH[((1 * 4 + wave) * 6 + kc) * 64 + lane];
        half8 brl = WL[((1 * 4 + wave) * 6 + kc) * 64 + lane];
        accz = __builtin_amdgcn_mfma_f32_16x16x32_f16(ahi, bzh, accz, 0, 0, 0);
        accz = __builtin_amdgcn_mfma_f32_16x16x32_f16(alo, bzh, accz, 0, 0, 0);
        accz = __builtin_amdgcn_mfma_f32_16x16x32_f16(ahi, bzl, accz, 0, 0, 0);
        accr = __builtin_amdgcn_mfma_f32_16x16x32_f16(ahi, brh, accr, 0, 0, 0);
        accr = __builtin_amdgcn_mfma_f32_16x16x32_f16(alo, brh, accr, 0, 0, 0);
        accr = __builtin_amdgcn_mfma_f32_16x16x32_f16(ahi, brl, accr, 0, 0, 0);
    }
    float bzv = bz[ch], brv = br[ch], bhv = bh[ch];
    float zreg[4], hvreg[4], rh[4];
#pragma unroll
    for (int rg = 0; rg < 4; rg++) {
        int nl = q * 4 + rg;                  // C/D row=(lane>>4)*4+reg -> node
        float z = 1.f / (1.f + __expf(-(accz[rg] + bzv)));
        float r = 1.f / (1.f + __expf(-(accr[rg] + brv)));
        float hv = xs_t[nl][128 + ch];
        zreg[rg] = z; hvreg[rg] = hv; rh[rg] = r * hv;
    }
    __syncthreads();                          // all zr A-frag reads of slots 128+ done
#pragma unroll
    for (int rg = 0; rg < 4; rg++) xs_t[q * 4 + rg][128 + ch] = rh[rg];
    __syncthreads();

    floatx4 acch = {0.f, 0.f, 0.f, 0.f};
#pragma unroll
    for (int kc = 0; kc < 6; kc++) {
        const float* xr = &xs_t[m][kc * 32 + q * 8];
        float4 xa = *(const float4*)xr;
        float4 xb = *(const float4*)(xr + 4);
        float xv[8] = {xa.x, xa.y, xa.z, xa.w, xb.x, xb.y, xb.z, xb.w};
        half8 ahi, alo;
#pragma unroll
        for (int j = 0; j < 8; j++) {
            _Float16 hj = (_Float16)xv[j];
            ahi[j] = hj;
            alo[j] = (_Float16)(xv[j] - (float)hj);
        }
        half8 bhh = WH[((2 * 4 + wave) * 6 + kc) * 64 + lane];
        half8 bhl = WL[((2 * 4 + wave) * 6 + kc) * 64 + lane];
        acch = __builtin_amdgcn_mfma_f32_16x16x32_f16(ahi, bhh, acch, 0, 0, 0);
        acch = __builtin_amdgcn_mfma_f32_16x16x32_f16(alo, bhh, acch, 0, 0, 0);
        acch = __builtin_amdgcn_mfma_f32_16x16x32_f16(ahi, bhl, acch, 0, 0, 0);
    }
    __syncthreads();                          // all hn A-frag reads done before overwrite
#pragma unroll
    for (int rg = 0; rg < 4; rg++) {
        int nl = q * 4 + rg;
        float pre = acch[rg] + bhv;
        float th = 2.f / (1.f + __expf(-2.f * pre)) - 1.f;
        float hv = hvreg[rg];
        xs_t[nl][ch] = hv + zreg[rg] * (th - hv);   // stage h' for coalesced write
    }
    __syncthreads();
    {
        int f = tid * 4;                      // 1024 floats = 16 nodes x 64
        int nl = f >> 6, c = f & 63;
        float4 v = *(const float4*)&xs_t[nl][c];
        int gi = ((base + nl) << 6) | c;
        *(float4*)&h[gi] = v;
        __half2 p0 = {__float2half(v.x), __float2half(v.y)};
        __half2 p1 = {__float2half(v.z), __float2half(v.w)};
        *(__half2*)&h16[gi] = p0;
        *(__half2*)&h16[gi + 2] = p1;
    }
}

// ---------------- output: out = h @ Wo^T + bo ----------------
__global__ void out_kernel(const float* __restrict__ h, const float* __restrict__ Wo,
                           const float* __restrict__ bo, float* __restrict__ out) {
    int wid = (blockIdx.x * blockDim.x + threadIdx.x) >> 6;
    int l = threadIdx.x & 63;
    if (wid >= NODES) return;
    float p = h[(wid << 6) | l] * Wo[l];
#pragma unroll
    for (int off = 32; off > 0; off >>= 1) p += __shfl_down(p, off);
    if (l == 0) out[wid] = p + bo[0];
}

extern "C" void kernel_launch(void* const* d_in, const int* in_sizes, int n_in,
                              void* d_out, int out_size, void* d_ws, size_t ws_size,
                              hipStream_t stream) {
    const float* attr = (const float*)d_in[0];
    const float* adj  = (const float*)d_in[1];
    const float* Wi   = (const float*)d_in[2];
    const float* bi   = (const float*)d_in[3];
    const float* Wz   = (const float*)d_in[4];
    const float* bz   = (const float*)d_in[5];
    const float* Wr   = (const float*)d_in[6];
    const float* br   = (const float*)d_in[7];
    const float* Wh   = (const float*)d_in[8];
    const float* bh   = (const float*)d_in[9];
    const float* Wo   = (const float*)d_in[10];
    const float* bo   = (const float*)d_in[11];
    float* out = (float*)d_out;

    char* ws = (char*)d_ws;
    size_t off = 0;
    auto carve = [&](size_t bytes) { void* p = ws + off; off = (off + bytes + 255) & ~(size_t)255; return p; };
    float* h      = (float*)carve((size_t)NODES * HD * 4);        // 8.4 MB
    __half* h16   = (__half*)carve((size_t)NODES * HD * 2);       // 4.2 MB
    float* xs     = (float*)carve((size_t)NODES * 192 * 4);       // 25.2 MB
    _Float16* wf_hi = (_Float16*)carve(3 * 4 * 6 * 64 * 8 * 2);   // 73.7 KB
    _Float16* wf_lo = (_Float16*)carve(3 * 4 * 6 * 64 * 8 * 2);   // 73.7 KB
    int* cnt_in   = (int*)carve((size_t)NODES * 4);
    int* cnt_out  = (int*)carve((size_t)NODES * 4);
    int* edge_in  = (int*)carve((size_t)NODES * ECAP * 4);        // 12.6 MB
    int* edge_out = (int*)carve((size_t)NODES * ECAP * 4);        // 12.6 MB

    hipMemsetAsync(cnt_out, 0, (size_t)NODES * 4, stream);        // cnt_in needs no memset

    init_h_kernel<<<NODES * HD / 256, 256, 0, stream>>>(attr, Wi, bi, h, h16);
    wprep_kernel<<<(3 * 4 * 6 * 64 * 8 + 255) / 256, 256, 0, stream>>>(Wz, Wr, Wh, wf_hi, wf_lo);
    count_rows_kernel<<<NODES / 4, 256, 0, stream>>>((const float4*)adj, cnt_in, edge_in);
    transpose_kernel<<<NODES / 4, 256, 0, stream>>>(cnt_in, edge_in, cnt_out, edge_out);

    for (int step = 0; step < STEPS; ++step) {
        aggregate_kernel<<<NODES * 2 * 64 / 256, 256, 0, stream>>>(
            (const __half2*)h16, h, cnt_in, edge_in, cnt_out, edge_out, xs);
        gate_kernel<<<NODES / 16, 256, 0, stream>>>(xs, wf_hi, wf_lo, bz, br, bh, h, h16);
    }
    out_kernel<<<NODES * HD / 256, 256, 0, stream>>>(h, Wo, bo, out);
}

// Round 10
// 1224.778 us; speedup vs baseline: 1.5328x; 1.0249x over previous
//
#include <hip/hip_runtime.h>
#include <hip/hip_fp16.h>
#include <stdint.h>

#define BB 8
#define NN 4096
#define ATTRD 16
#define HD 64
#define STEPS 8
#define NODES (BB*NN)      // 32768
#define ECAP 96            // nnz/row ~ Poisson(41); P(>=96) astronomically small
#define KPAD 196           // xs_t row stride in floats

typedef _Float16 half8 __attribute__((ext_vector_type(8)));
typedef float floatx4 __attribute__((ext_vector_type(4)));
typedef unsigned long long ull;

// ---------------- init: h = relu(attr @ Wi^T + bi); fp32 master + fp16 mirror + zero pad row ----
__global__ void init_h_kernel(const float* __restrict__ attr, const float* __restrict__ Wi,
                              const float* __restrict__ bi, float* __restrict__ h,
                              __half* __restrict__ h16) {
    int idx = blockIdx.x * blockDim.x + threadIdx.x;   // node*64 + l
    if (idx >= (NODES + 1) * HD) return;
    if (idx >= NODES * HD) {                           // dummy row (index NODES): zeros
        h16[idx] = __float2half(0.f);
        return;
    }
    int node = idx >> 6, l = idx & 63;
    const float* a = attr + node * ATTRD;
    const float* w = Wi + l * ATTRD;
    float acc = bi[l];
#pragma unroll
    for (int k = 0; k < ATTRD; k++) acc += a[k] * w[k];
    float r = acc > 0.f ? acc : 0.f;
    h[idx] = r;
    h16[idx] = __float2half(r);
}

// ---------------- weight prep: split-fp16 MFMA B-fragments (r8-proven) ----------------
__global__ void wprep_kernel(const float* __restrict__ Wz, const float* __restrict__ Wr,
                             const float* __restrict__ Wh,
                             _Float16* __restrict__ wf_hi, _Float16* __restrict__ wf_lo) {
    int t = blockIdx.x * blockDim.x + threadIdx.x;
    if (t >= 3 * 4 * 6 * 64 * 8) return;
    int mat = t / 12288, rem = t % 12288;
    int tile = rem / 3072, rem2 = rem % 3072;
    int kc = rem2 / 512, rem3 = rem2 % 512;
    int lane = rem3 / 8, j = rem3 % 8;
    int k = kc * 32 + (lane >> 4) * 8 + j;
    int och = tile * 16 + (lane & 15);
    const float* W = (mat == 0) ? Wz : (mat == 1) ? Wr : Wh;
    float v = W[och * 192 + k];
    _Float16 hi = (_Float16)v;
    wf_hi[t] = hi;
    wf_lo[t] = (_Float16)(v - (float)hi);
}

// ---------------- in-edge ELL build: one wave per adjacency row, atomic-free (r9) ----------------
__global__ __launch_bounds__(256) void count_rows_kernel(const float4* __restrict__ A4,
                                                         int* __restrict__ cnt_in,
                                                         int* __restrict__ edge_in) {
    int wave = threadIdx.x >> 6, l = threadIdx.x & 63;
    int row = blockIdx.x * 4 + wave;                   // 0..32767
    const float4* rp = A4 + (size_t)row * 1024;
    ull mask_lt = (l == 63) ? ~0ull >> 1 : ((1ull << (l + 1)) - 1) >> 1; // bits < l
    float4 v[16];
#pragma unroll
    for (int t = 0; t < 16; t++) v[t] = rp[t * 64 + l];   // 16 coalesced 1KB loads in flight
    int colbase = (row >> 12) << 12;                      // batch * 4096
    int run = 0;
    int* erow = edge_in + row * ECAP;
#pragma unroll
    for (int t = 0; t < 16; t++) {
        ull b0 = __ballot(v[t].x != 0.f);
        ull b1 = __ballot(v[t].y != 0.f);
        ull b2 = __ballot(v[t].z != 0.f);
        ull b3 = __ballot(v[t].w != 0.f);
        int pre = __popcll(b0 & mask_lt) + __popcll(b1 & mask_lt) +
                  __popcll(b2 & mask_lt) + __popcll(b3 & mask_lt);
        float vv[4] = {v[t].x, v[t].y, v[t].z, v[t].w};
        int jbase = (t * 64 + l) * 4;
        int inner = 0;
#pragma unroll
        for (int q = 0; q < 4; q++) {
            if (vv[q] != 0.f) {
                int slot = run + pre + inner;
                if (slot < ECAP) erow[slot] = colbase | (jbase + q);
                inner++;
            }
        }
        run += __popcll(b0) + __popcll(b1) + __popcll(b2) + __popcll(b3);
    }
    if (l == 0) cnt_in[row] = run;
}

// ---------------- out-edge build: transpose the ELL (reads 5.4 MB, not 537 MB) ----------------
__global__ __launch_bounds__(256) void transpose_kernel(const int* __restrict__ cnt_in,
                                                        const int* __restrict__ edge_in,
                                                        int* __restrict__ cnt_out,
                                                        int* __restrict__ edge_out) {
    int wave = threadIdx.x >> 6, l = threadIdx.x & 63;
    int row = blockIdx.x * 4 + wave;
    int n = cnt_in[row]; if (n > ECAP) n = ECAP;
    for (int s = l; s < n; s += 64) {
        int j = edge_in[row * ECAP + s];
        int s2 = atomicAdd(&cnt_out[j], 1);
        if (s2 < ECAP) edge_out[j * ECAP + s2] = row;
    }
}

// ---------------- aggregation: xs = [A@h | A^T@h | h] — wide-payload gathers ----------------
// One wave per (node,dir). Edge indices preloaded into regs (2 wave-loads), distributed
// via __shfl. Gather: 16 B/lane uint4 (8 fp16 ch), 8 lanes/row -> 8 edges per load inst.
// OOB lanes gather the zeroed dummy row (index NODES). 3-step shfl_xor reduction.
__global__ __launch_bounds__(256) void aggregate_kernel(
        const uint4* __restrict__ h4, const float* __restrict__ h,
        const int* __restrict__ cnt_in, const int* __restrict__ edge_in,
        const int* __restrict__ cnt_out, const int* __restrict__ edge_out,
        float* __restrict__ xs) {
    int bid = blockIdx.x;
    int batch = bid & 7;                       // XCD swizzle
    int group = bid >> 3;
    int wave = threadIdx.x >> 6;
    int pair = group * 4 + wave;
    int node = (batch << 12) + (pair >> 1);
    int dir = pair & 1;
    int l = threadIdx.x & 63;
    int sub = l >> 3;                          // edge slot within group of 8
    int part = l & 7;                          // 16B chunk within 128B row
    int n = dir ? cnt_out[node] : cnt_in[node];
    if (n > ECAP) n = ECAP;
    const int* erow = (dir ? edge_out : edge_in) + node * ECAP;
    // whole edge list -> registers (upfront; garbage beyond n never selected)
    int e0 = erow[l];
    int e1 = erow[64 + (l & 31)];
    float a0 = 0.f, a1 = 0.f, a2 = 0.f, a3 = 0.f, a4 = 0.f, a5 = 0.f, a6 = 0.f, a7 = 0.f;
    for (int s = 0; s < n; s += 8) {
        int il = s + sub;
        int gidx = (il < 64) ? __shfl(e0, il) : __shfl(e1, il - 64);
        gidx = (il < n) ? gidx : NODES;        // dummy zero row
        uint4 g = h4[(gidx << 3) | part];
        float2 p0 = __half22float2(*(__half2*)&g.x);
        float2 p1 = __half22float2(*(__half2*)&g.y);
        float2 p2 = __half22float2(*(__half2*)&g.z);
        float2 p3 = __half22float2(*(__half2*)&g.w);
        a0 += p0.x; a1 += p0.y; a2 += p1.x; a3 += p1.y;
        a4 += p2.x; a5 += p2.y; a6 += p3.x; a7 += p3.y;
    }
    // reduce over the 8 sub-groups (partners share `part`)
#pragma unroll
    for (int off = 8; off < 64; off <<= 1) {
        a0 += __shfl_xor(a0, off); a1 += __shfl_xor(a1, off);
        a2 += __shfl_xor(a2, off); a3 += __shfl_xor(a3, off);
        a4 += __shfl_xor(a4, off); a5 += __shfl_xor(a5, off);
        a6 += __shfl_xor(a6, off); a7 += __shfl_xor(a7, off);
    }
    if (l < 8) {                               // lane l holds channels l*8..l*8+7
        float4 s0 = {a0, a1, a2, a3};
        float4 s1 = {a4, a5, a6, a7};
        float* dst = xs + node * 192 + dir * 64 + l * 8;
        *(float4*)dst = s0;
        *(float4*)(dst + 4) = s1;
    }
    if (dir == 0) xs[node * 192 + 128 + l] = h[(node << 6) | l];  // fp32 master h slot
}

// ---------------- gates via split-fp16 MFMA (r8-proven, fp32-accurate) ----------------
__global__ __launch_bounds__(256) void gate_kernel(
        const float* __restrict__ xs_g,
        const _Float16* __restrict__ wf_hi, const _Float16* __restrict__ wf_lo,
        const float* __restrict__ bz, const float* __restrict__ br,
        const float* __restrict__ bh,
        float* __restrict__ h, __half* __restrict__ h16) {
    __shared__ float xs_t[16][KPAD];     // 12.5 KB
    int bid = blockIdx.x;
    int base = ((bid & 7) << 12) | ((bid >> 3) << 4);   // XCD-swizzled node base
    int tid = threadIdx.x;
    {
        const float4* src = (const float4*)(xs_g + base * 192);
#pragma unroll
        for (int i = 0; i < 3; i++) {
            int idx = tid + i * 256;          // 768 float4s = 16 nodes x 48
            float4 v = src[idx];
            int nl = idx / 48, kb = (idx % 48) * 4;
            *(float4*)&xs_t[nl][kb] = v;
        }
    }
    __syncthreads();
    int wave = tid >> 6, lane = tid & 63;
    int m = lane & 15, q = lane >> 4;
    int ch = wave * 16 + m;                   // global output channel (C/D col=lane&15)
    const half8* WH = (const half8*)wf_hi;
    const half8* WL = (const half8*)wf_lo;

    floatx4 accz = {0.f, 0.f, 0.f, 0.f};
    floatx4 accr = {0.f, 0.f, 0.f, 0.f};
#pragma unroll
    for (int kc = 0; kc < 6; kc++) {
        const float* xr = &xs_t[m][kc * 32 + q * 8];
        float4 xa = *(const float4*)xr;
        float4 xb = *(const float4*)(xr + 4);
        float xv[8] = {xa.x, xa.y, xa.z, xa.w, xb.x, xb.y, xb.z, xb.w};
        half8 ahi, alo;
#pragma unroll
        for (int j = 0; j < 8; j++) {
            _Float16 hj = (_Float16)xv[j];
            ahi[j] = hj;
            alo[j] = (_Float16)(xv[j] - (float)hj);
        }
        half8 bzh = WH[((0 * 4 + wave) * 6 + kc) * 64 + lane];
        half8 bzl = WL[((0 * 4 + wave) * 6 + kc) * 64 + lane];
        half8 brh = WH[((1 * 4 + wave) * 6 + kc) * 64 + lane];
        half8 brl = WL[((1 * 4 + wave) * 6 + kc) * 64 + lane];
        accz = __builtin_amdgcn_mfma_f32_16x16x32_f16(ahi, bzh, accz, 0, 0, 0);
        accz = __builtin_amdgcn_mfma_f32_16x16x32_f16(alo, bzh, accz, 0, 0, 0);
        accz = __builtin_amdgcn_mfma_f32_16x16x32_f16(ahi, bzl, accz, 0, 0, 0);
        accr = __builtin_amdgcn_mfma_f32_16x16x32_f16(ahi, brh, accr, 0, 0, 0);
        accr = __builtin_amdgcn_mfma_f32_16x16x32_f16(alo, brh, accr, 0, 0, 0);
        accr = __builtin_amdgcn_mfma_f32_16x16x32_f16(ahi, brl, accr, 0, 0, 0);
    }
    float bzv = bz[ch], brv = br[ch], bhv = bh[ch];
    float zreg[4], hvreg[4], rh[4];
#pragma unroll
    for (int rg = 0; rg < 4; rg++) {
        int nl = q * 4 + rg;                  // C/D row=(lane>>4)*4+reg -> node
        float z = 1.f / (1.f + __expf(-(accz[rg] + bzv)));
        float r = 1.f / (1.f + __expf(-(accr[rg] + brv)));
        float hv = xs_t[nl][128 + ch];
        zreg[rg] = z; hvreg[rg] = hv; rh[rg] = r * hv;
    }
    __syncthreads();                          // all zr A-frag reads of slots 128+ done
#pragma unroll
    for (int rg = 0; rg < 4; rg++) xs_t[q * 4 + rg][128 + ch] = rh[rg];
    __syncthreads();

    floatx4 acch = {0.f, 0.f, 0.f, 0.f};
#pragma unroll
    for (int kc = 0; kc < 6; kc++) {
        const float* xr = &xs_t[m][kc * 32 + q * 8];
        float4 xa = *(const float4*)xr;
        float4 xb = *(const float4*)(xr + 4);
        float xv[8] = {xa.x, xa.y, xa.z, xa.w, xb.x, xb.y, xb.z, xb.w};
        half8 ahi, alo;
#pragma unroll
        for (int j = 0; j < 8; j++) {
            _Float16 hj = (_Float16)xv[j];
            ahi[j] = hj;
            alo[j] = (_Float16)(xv[j] - (float)hj);
        }
        half8 bhh = WH[((2 * 4 + wave) * 6 + kc) * 64 + lane];
        half8 bhl = WL[((2 * 4 + wave) * 6 + kc) * 64 + lane];
        acch = __builtin_amdgcn_mfma_f32_16x16x32_f16(ahi, bhh, acch, 0, 0, 0);
        acch = __builtin_amdgcn_mfma_f32_16x16x32_f16(alo, bhh, acch, 0, 0, 0);
        acch = __builtin_amdgcn_mfma_f32_16x16x32_f16(ahi, bhl, acch, 0, 0, 0);
    }
    __syncthreads();                          // all hn A-frag reads done before overwrite
#pragma unroll
    for (int rg = 0; rg < 4; rg++) {
        int nl = q * 4 + rg;
        float pre = acch[rg] + bhv;
        float th = 2.f / (1.f + __expf(-2.f * pre)) - 1.f;
        float hv = hvreg[rg];
        xs_t[nl][ch] = hv + zreg[rg] * (th - hv);   // stage h' for coalesced write
    }
    __syncthreads();
    {
        int f = tid * 4;                      // 1024 floats = 16 nodes x 64
        int nl = f >> 6, c = f & 63;
        float4 v = *(const float4*)&xs_t[nl][c];
        int gi = ((base + nl) << 6) | c;
        *(float4*)&h[gi] = v;
        __half2 p0 = {__float2half(v.x), __float2half(v.y)};
        __half2 p1 = {__float2half(v.z), __float2half(v.w)};
        *(__half2*)&h16[gi] = p0;
        *(__half2*)&h16[gi + 2] = p1;
    }
}

// ---------------- output: out = h @ Wo^T + bo ----------------
__global__ void out_kernel(const float* __restrict__ h, const float* __restrict__ Wo,
                           const float* __restrict__ bo, float* __restrict__ out) {
    int wid = (blockIdx.x * blockDim.x + threadIdx.x) >> 6;
    int l = threadIdx.x & 63;
    if (wid >= NODES) return;
    float p = h[(wid << 6) | l] * Wo[l];
#pragma unroll
    for (int off = 32; off > 0; off >>= 1) p += __shfl_down(p, off);
    if (l == 0) out[wid] = p + bo[0];
}

extern "C" void kernel_launch(void* const* d_in, const int* in_sizes, int n_in,
                              void* d_out, int out_size, void* d_ws, size_t ws_size,
                              hipStream_t stream) {
    const float* attr = (const float*)d_in[0];
    const float* adj  = (const float*)d_in[1];
    const float* Wi   = (const float*)d_in[2];
    const float* bi   = (const float*)d_in[3];
    const float* Wz   = (const float*)d_in[4];
    const float* bz   = (const float*)d_in[5];
    const float* Wr   = (const float*)d_in[6];
    const float* br   = (const float*)d_in[7];
    const float* Wh   = (const float*)d_in[8];
    const float* bh   = (const float*)d_in[9];
    const float* Wo   = (const float*)d_in[10];
    const float* bo   = (const float*)d_in[11];
    float* out = (float*)d_out;

    char* ws = (char*)d_ws;
    size_t off = 0;
    auto carve = [&](size_t bytes) { void* p = ws + off; off = (off + bytes + 255) & ~(size_t)255; return p; };
    float* h      = (float*)carve((size_t)NODES * HD * 4);            // 8.4 MB
    __half* h16   = (__half*)carve((size_t)(NODES + 1) * HD * 2);     // 4.2 MB (+dummy row)
    float* xs     = (float*)carve((size_t)NODES * 192 * 4);           // 25.2 MB
    _Float16* wf_hi = (_Float16*)carve(3 * 4 * 6 * 64 * 8 * 2);       // 73.7 KB
    _Float16* wf_lo = (_Float16*)carve(3 * 4 * 6 * 64 * 8 * 2);       // 73.7 KB
    int* cnt_in   = (int*)carve((size_t)NODES * 4);
    int* cnt_out  = (int*)carve((size_t)NODES * 4);
    int* edge_in  = (int*)carve((size_t)NODES * ECAP * 4);            // 12.6 MB
    int* edge_out = (int*)carve((size_t)NODES * ECAP * 4);            // 12.6 MB

    hipMemsetAsync(cnt_out, 0, (size_t)NODES * 4, stream);            // cnt_in needs no memset

    init_h_kernel<<<((NODES + 1) * HD + 255) / 256, 256, 0, stream>>>(attr, Wi, bi, h, h16);
    wprep_kernel<<<(3 * 4 * 6 * 64 * 8 + 255) / 256, 256, 0, stream>>>(Wz, Wr, Wh, wf_hi, wf_lo);
    count_rows_kernel<<<NODES / 4, 256, 0, stream>>>((const float4*)adj, cnt_in, edge_in);
    transpose_kernel<<<NODES / 4, 256, 0, stream>>>(cnt_in, edge_in, cnt_out, edge_out);

    for (int step = 0; step < STEPS; ++step) {
        aggregate_kernel<<<NODES * 2 * 64 / 256, 256, 0, stream>>>(
            (const uint4*)h16, h, cnt_in, edge_in, cnt_out, edge_out, xs);
        gate_kernel<<<NODES / 16, 256, 0, stream>>>(xs, wf_hi, wf_lo, bz, br, bh, h, h16);
    }
    out_kernel<<<NODES * HD / 256, 256, 0, stream>>>(h, Wo, bo, out);
}

// Round 11
// 1180.637 us; speedup vs baseline: 1.5901x; 1.0374x over previous
//
#include <hip/hip_runtime.h>
#include <hip/hip_fp16.h>
#include <stdint.h>

#define BB 8
#define NN 4096
#define ATTRD 16
#define HD 64
#define STEPS 8
#define NODES (BB*NN)      // 32768
#define ECAP 96            // nnz/row ~ Poisson(41); P(>=96) astronomically small
#define KPAD 196           // xs_t row stride in floats

typedef _Float16 half8 __attribute__((ext_vector_type(8)));
typedef float floatx4 __attribute__((ext_vector_type(4)));
typedef unsigned long long ull;

// ---------------- init: h = relu(attr @ Wi^T + bi); fp32 master + fp16 mirror + zero pad row ----
__global__ void init_h_kernel(const float* __restrict__ attr, const float* __restrict__ Wi,
                              const float* __restrict__ bi, float* __restrict__ h,
                              __half* __restrict__ h16) {
    int idx = blockIdx.x * blockDim.x + threadIdx.x;   // node*64 + l
    if (idx >= (NODES + 1) * HD) return;
    if (idx >= NODES * HD) {                           // dummy row (index NODES): zeros
        h16[idx] = __float2half(0.f);
        return;
    }
    int node = idx >> 6, l = idx & 63;
    const float* a = attr + node * ATTRD;
    const float* w = Wi + l * ATTRD;
    float acc = bi[l];
#pragma unroll
    for (int k = 0; k < ATTRD; k++) acc += a[k] * w[k];
    float r = acc > 0.f ? acc : 0.f;
    h[idx] = r;
    h16[idx] = __float2half(r);
}

// ---------------- weight prep: split-fp16 MFMA B-fragments (r8-proven) ----------------
__global__ void wprep_kernel(const float* __restrict__ Wz, const float* __restrict__ Wr,
                             const float* __restrict__ Wh,
                             _Float16* __restrict__ wf_hi, _Float16* __restrict__ wf_lo) {
    int t = blockIdx.x * blockDim.x + threadIdx.x;
    if (t >= 3 * 4 * 6 * 64 * 8) return;
    int mat = t / 12288, rem = t % 12288;
    int tile = rem / 3072, rem2 = rem % 3072;
    int kc = rem2 / 512, rem3 = rem2 % 512;
    int lane = rem3 / 8, j = rem3 % 8;
    int k = kc * 32 + (lane >> 4) * 8 + j;
    int och = tile * 16 + (lane & 15);
    const float* W = (mat == 0) ? Wz : (mat == 1) ? Wr : Wh;
    float v = W[och * 192 + k];
    _Float16 hi = (_Float16)v;
    wf_hi[t] = hi;
    wf_lo[t] = (_Float16)(v - (float)hi);
}

// ---------------- ELL build: one wave per row; in-edges atomic-free, out-edges folded in ------
// (r8 vs r9 measured: atomic-in-stream == split two-kernel. Folding kills transpose's 18 MB r/w.)
__global__ __launch_bounds__(256) void count_rows_kernel(const float4* __restrict__ A4,
                                                         int* __restrict__ cnt_in,
                                                         int* __restrict__ edge_in,
                                                         int* __restrict__ cnt_out,
                                                         int* __restrict__ edge_out) {
    int wave = threadIdx.x >> 6, l = threadIdx.x & 63;
    int row = blockIdx.x * 4 + wave;                   // 0..32767
    const float4* rp = A4 + (size_t)row * 1024;
    ull mask_lt = (l == 63) ? ~0ull >> 1 : ((1ull << (l + 1)) - 1) >> 1; // bits < l
    float4 v[16];
#pragma unroll
    for (int t = 0; t < 16; t++) v[t] = rp[t * 64 + l];   // 16 coalesced 1KB loads in flight
    int colbase = (row >> 12) << 12;                      // batch * 4096
    int run = 0;
    int* erow = edge_in + row * ECAP;
#pragma unroll
    for (int t = 0; t < 16; t++) {
        ull b0 = __ballot(v[t].x != 0.f);
        ull b1 = __ballot(v[t].y != 0.f);
        ull b2 = __ballot(v[t].z != 0.f);
        ull b3 = __ballot(v[t].w != 0.f);
        int pre = __popcll(b0 & mask_lt) + __popcll(b1 & mask_lt) +
                  __popcll(b2 & mask_lt) + __popcll(b3 & mask_lt);
        float vv[4] = {v[t].x, v[t].y, v[t].z, v[t].w};
        int jbase = (t * 64 + l) * 4;
        int inner = 0;
#pragma unroll
        for (int q = 0; q < 4; q++) {
            if (vv[q] != 0.f) {
                int col = colbase | (jbase + q);
                int slot = run + pre + inner;
                if (slot < ECAP) erow[slot] = col;
                inner++;
                int s2 = atomicAdd(&cnt_out[col], 1);      // distinct cols per lane
                if (s2 < ECAP) edge_out[col * ECAP + s2] = row;
            }
        }
        run += __popcll(b0) + __popcll(b1) + __popcll(b2) + __popcll(b3);
    }
    if (l == 0) cnt_in[row] = run;
}

// ---------------- aggregation: xs = [A@h | A^T@h | h] — dual-dir waves, wide gathers ----------
// One wave per NODE: in/out gather chains interleaved (2x MLP), prologue+epilogue amortized.
// Gather 16 B/lane (8 fp16 ch), 8 lanes/row -> 8 edges per load inst; OOB -> zeroed dummy row.
__global__ __launch_bounds__(256) void aggregate_kernel(
        const uint4* __restrict__ h4, const float* __restrict__ h,
        const int* __restrict__ cnt_in, const int* __restrict__ edge_in,
        const int* __restrict__ cnt_out, const int* __restrict__ edge_out,
        float* __restrict__ xs) {
    int bid = blockIdx.x;                      // 8192 blocks
    int batch = bid & 7;                       // XCD swizzle
    int group = bid >> 3;                      // 0..1023
    int wave = threadIdx.x >> 6;
    int node = (batch << 12) + group * 4 + wave;
    int l = threadIdx.x & 63;
    int sub = l >> 3;                          // edge slot within volley of 8
    int part = l & 7;                          // 16B chunk within 128B row
    int ni = cnt_in[node];  if (ni > ECAP) ni = ECAP;
    int no = cnt_out[node]; if (no > ECAP) no = ECAP;
    const int* ei = edge_in + node * ECAP;
    const int* eo = edge_out + node * ECAP;
    // whole edge lists -> registers (4 wave-wide loads, in flight together)
    int ei0 = ei[l], ei1 = ei[64 + (l & 31)];
    int eo0 = eo[l], eo1 = eo[64 + (l & 31)];
    float ai0 = 0.f, ai1 = 0.f, ai2 = 0.f, ai3 = 0.f, ai4 = 0.f, ai5 = 0.f, ai6 = 0.f, ai7 = 0.f;
    float ao0 = 0.f, ao1 = 0.f, ao2 = 0.f, ao3 = 0.f, ao4 = 0.f, ao5 = 0.f, ao6 = 0.f, ao7 = 0.f;
    int nmax = ni > no ? ni : no;
    for (int s = 0; s < nmax; s += 8) {
        int il = s + sub;
        int gi = (il < 64) ? __shfl(ei0, il) : __shfl(ei1, il - 64);
        int go = (il < 64) ? __shfl(eo0, il) : __shfl(eo1, il - 64);
        gi = (il < ni) ? gi : NODES;           // dummy zero row
        go = (il < no) ? go : NODES;
        uint4 gA = h4[(gi << 3) | part];       // two independent gathers in flight
        uint4 gB = h4[(go << 3) | part];
        float2 pA0 = __half22float2(*(__half2*)&gA.x);
        float2 pA1 = __half22float2(*(__half2*)&gA.y);
        float2 pA2 = __half22float2(*(__half2*)&gA.z);
        float2 pA3 = __half22float2(*(__half2*)&gA.w);
        ai0 += pA0.x; ai1 += pA0.y; ai2 += pA1.x; ai3 += pA1.y;
        ai4 += pA2.x; ai5 += pA2.y; ai6 += pA3.x; ai7 += pA3.y;
        float2 pB0 = __half22float2(*(__half2*)&gB.x);
        float2 pB1 = __half22float2(*(__half2*)&gB.y);
        float2 pB2 = __half22float2(*(__half2*)&gB.z);
        float2 pB3 = __half22float2(*(__half2*)&gB.w);
        ao0 += pB0.x; ao1 += pB0.y; ao2 += pB1.x; ao3 += pB1.y;
        ao4 += pB2.x; ao5 += pB2.y; ao6 += pB3.x; ao7 += pB3.y;
    }
    // reduce over the 8 sub-groups (partners share `part`)
#pragma unroll
    for (int off = 8; off < 64; off <<= 1) {
        ai0 += __shfl_xor(ai0, off); ai1 += __shfl_xor(ai1, off);
        ai2 += __shfl_xor(ai2, off); ai3 += __shfl_xor(ai3, off);
        ai4 += __shfl_xor(ai4, off); ai5 += __shfl_xor(ai5, off);
        ai6 += __shfl_xor(ai6, off); ai7 += __shfl_xor(ai7, off);
        ao0 += __shfl_xor(ao0, off); ao1 += __shfl_xor(ao1, off);
        ao2 += __shfl_xor(ao2, off); ao3 += __shfl_xor(ao3, off);
        ao4 += __shfl_xor(ao4, off); ao5 += __shfl_xor(ao5, off);
        ao6 += __shfl_xor(ao6, off); ao7 += __shfl_xor(ao7, off);
    }
    if (l < 8) {                               // lane l holds channels l*8..l*8+7
        float* dst = xs + node * 192;
        float4 si0 = {ai0, ai1, ai2, ai3};
        float4 si1 = {ai4, ai5, ai6, ai7};
        float4 so0 = {ao0, ao1, ao2, ao3};
        float4 so1 = {ao4, ao5, ao6, ao7};
        *(float4*)(dst + l * 8)      = si0;
        *(float4*)(dst + l * 8 + 4)  = si1;
        *(float4*)(dst + 64 + l * 8)     = so0;
        *(float4*)(dst + 64 + l * 8 + 4) = so1;
    }
    xs[node * 192 + 128 + l] = h[(node << 6) | l];   // fp32 master h slot
}

// ---------------- gates via split-fp16 MFMA (r8-proven, fp32-accurate) ----------------
__global__ __launch_bounds__(256) void gate_kernel(
        const float* __restrict__ xs_g,
        const _Float16* __restrict__ wf_hi, const _Float16* __restrict__ wf_lo,
        const float* __restrict__ bz, const float* __restrict__ br,
        const float* __restrict__ bh,
        float* __restrict__ h, __half* __restrict__ h16) {
    __shared__ float xs_t[16][KPAD];     // 12.5 KB
    int bid = blockIdx.x;
    int base = ((bid & 7) << 12) | ((bid >> 3) << 4);   // XCD-swizzled node base
    int tid = threadIdx.x;
    {
        const float4* src = (const float4*)(xs_g + base * 192);
#pragma unroll
        for (int i = 0; i < 3; i++) {
            int idx = tid + i * 256;          // 768 float4s = 16 nodes x 48
            float4 v = src[idx];
            int nl = idx / 48, kb = (idx % 48) * 4;
            *(float4*)&xs_t[nl][kb] = v;
        }
    }
    __syncthreads();
    int wave = tid >> 6, lane = tid & 63;
    int m = lane & 15, q = lane >> 4;
    int ch = wave * 16 + m;                   // global output channel (C/D col=lane&15)
    const half8* WH = (const half8*)wf_hi;
    const half8* WL = (const half8*)wf_lo;

    floatx4 accz = {0.f, 0.f, 0.f, 0.f};
    floatx4 accr = {0.f, 0.f, 0.f, 0.f};
#pragma unroll
    for (int kc = 0; kc < 6; kc++) {
        const float* xr = &xs_t[m][kc * 32 + q * 8];
        float4 xa = *(const float4*)xr;
        float4 xb = *(const float4*)(xr + 4);
        float xv[8] = {xa.x, xa.y, xa.z, xa.w, xb.x, xb.y, xb.z, xb.w};
        half8 ahi, alo;
#pragma unroll
        for (int j = 0; j < 8; j++) {
            _Float16 hj = (_Float16)xv[j];
            ahi[j] = hj;
            alo[j] = (_Float16)(xv[j] - (float)hj);
        }
        half8 bzh = WH[((0 * 4 + wave) * 6 + kc) * 64 + lane];
        half8 bzl = WL[((0 * 4 + wave) * 6 + kc) * 64 + lane];
        half8 brh = WH[((1 * 4 + wave) * 6 + kc) * 64 + lane];
        half8 brl = WL[((1 * 4 + wave) * 6 + kc) * 64 + lane];
        accz = __builtin_amdgcn_mfma_f32_16x16x32_f16(ahi, bzh, accz, 0, 0, 0);
        accz = __builtin_amdgcn_mfma_f32_16x16x32_f16(alo, bzh, accz, 0, 0, 0);
        accz = __builtin_amdgcn_mfma_f32_16x16x32_f16(ahi, bzl, accz, 0, 0, 0);
        accr = __builtin_amdgcn_mfma_f32_16x16x32_f16(ahi, brh, accr, 0, 0, 0);
        accr = __builtin_amdgcn_mfma_f32_16x16x32_f16(alo, brh, accr, 0, 0, 0);
        accr = __builtin_amdgcn_mfma_f32_16x16x32_f16(ahi, brl, accr, 0, 0, 0);
    }
    float bzv = bz[ch], brv = br[ch], bhv = bh[ch];
    float zreg[4], hvreg[4], rh[4];
#pragma unroll
    for (int rg = 0; rg < 4; rg++) {
        int nl = q * 4 + rg;                  // C/D row=(lane>>4)*4+reg -> node
        float z = 1.f / (1.f + __expf(-(accz[rg] + bzv)));
        float r = 1.f / (1.f + __expf(-(accr[rg] + brv)));
        float hv = xs_t[nl][128 + ch];
        zreg[rg] = z; hvreg[rg] = hv; rh[rg] = r * hv;
    }
    __syncthreads();                          // all zr A-frag reads of slots 128+ done
#pragma unroll
    for (int rg = 0; rg < 4; rg++) xs_t[q * 4 + rg][128 + ch] = rh[rg];
    __syncthreads();

    floatx4 acch = {0.f, 0.f, 0.f, 0.f};
#pragma unroll
    for (int kc = 0; kc < 6; kc++) {
        const float* xr = &xs_t[m][kc * 32 + q * 8];
        float4 xa = *(const float4*)xr;
        float4 xb = *(const float4*)(xr + 4);
        float xv[8] = {xa.x, xa.y, xa.z, xa.w, xb.x, xb.y, xb.z, xb.w};
        half8 ahi, alo;
#pragma unroll
        for (int j = 0; j < 8; j++) {
            _Float16 hj = (_Float16)xv[j];
            ahi[j] = hj;
            alo[j] = (_Float16)(xv[j] - (float)hj);
        }
        half8 bhh = WH[((2 * 4 + wave) * 6 + kc) * 64 + lane];
        half8 bhl = WL[((2 * 4 + wave) * 6 + kc) * 64 + lane];
        acch = __builtin_amdgcn_mfma_f32_16x16x32_f16(ahi, bhh, acch, 0, 0, 0);
        acch = __builtin_amdgcn_mfma_f32_16x16x32_f16(alo, bhh, acch, 0, 0, 0);
        acch = __builtin_amdgcn_mfma_f32_16x16x32_f16(ahi, bhl, acch, 0, 0, 0);
    }
    __syncthreads();                          // all hn A-frag reads done before overwrite
#pragma unroll
    for (int rg = 0; rg < 4; rg++) {
        int nl = q * 4 + rg;
        float pre = acch[rg] + bhv;
        float th = 2.f / (1.f + __expf(-2.f * pre)) - 1.f;
        float hv = hvreg[rg];
        xs_t[nl][ch] = hv + zreg[rg] * (th - hv);   // stage h' for coalesced write
    }
    __syncthreads();
    {
        int f = tid * 4;                      // 1024 floats = 16 nodes x 64
        int nl = f >> 6, c = f & 63;
        float4 v = *(const float4*)&xs_t[nl][c];
        int gi = ((base + nl) << 6) | c;
        *(float4*)&h[gi] = v;
        __half2 p0 = {__float2half(v.x), __float2half(v.y)};
        __half2 p1 = {__float2half(v.z), __float2half(v.w)};
        *(__half2*)&h16[gi] = p0;
        *(__half2*)&h16[gi + 2] = p1;
    }
}

// ---------------- output: out = h @ Wo^T + bo ----------------
__global__ void out_kernel(const float* __restrict__ h, const float* __restrict__ Wo,
                           const float* __restrict__ bo, float* __restrict__ out) {
    int wid = (blockIdx.x * blockDim.x + threadIdx.x) >> 6;
    int l = threadIdx.x & 63;
    if (wid >= NODES) return;
    float p = h[(wid << 6) | l] * Wo[l];
#pragma unroll
    for (int off = 32; off > 0; off >>= 1) p += __shfl_down(p, off);
    if (l == 0) out[wid] = p + bo[0];
}

extern "C" void kernel_launch(void* const* d_in, const int* in_sizes, int n_in,
                              void* d_out, int out_size, void* d_ws, size_t ws_size,
                              hipStream_t stream) {
    const float* attr = (const float*)d_in[0];
    const float* adj  = (const float*)d_in[1];
    const float* Wi   = (const float*)d_in[2];
    const float* bi   = (const float*)d_in[3];
    const float* Wz   = (const float*)d_in[4];
    const float* bz   = (const float*)d_in[5];
    const float* Wr   = (const float*)d_in[6];
    const float* br   = (const float*)d_in[7];
    const float* Wh   = (const float*)d_in[8];
    const float* bh   = (const float*)d_in[9];
    const float* Wo   = (const float*)d_in[10];
    const float* bo   = (const float*)d_in[11];
    float* out = (float*)d_out;

    char* ws = (char*)d_ws;
    size_t off = 0;
    auto carve = [&](size_t bytes) { void* p = ws + off; off = (off + bytes + 255) & ~(size_t)255; return p; };
    float* h      = (float*)carve((size_t)NODES * HD * 4);            // 8.4 MB
    __half* h16   = (__half*)carve((size_t)(NODES + 1) * HD * 2);     // 4.2 MB (+dummy row)
    float* xs     = (float*)carve((size_t)NODES * 192 * 4);           // 25.2 MB
    _Float16* wf_hi = (_Float16*)carve(3 * 4 * 6 * 64 * 8 * 2);       // 73.7 KB
    _Float16* wf_lo = (_Float16*)carve(3 * 4 * 6 * 64 * 8 * 2);       // 73.7 KB
    int* cnt_in   = (int*)carve((size_t)NODES * 4);
    int* cnt_out  = (int*)carve((size_t)NODES * 4);
    int* edge_in  = (int*)carve((size_t)NODES * ECAP * 4);            // 12.6 MB
    int* edge_out = (int*)carve((size_t)NODES * ECAP * 4);            // 12.6 MB

    hipMemsetAsync(cnt_out, 0, (size_t)NODES * 4, stream);            // cnt_in needs no memset

    init_h_kernel<<<((NODES + 1) * HD + 255) / 256, 256, 0, stream>>>(attr, Wi, bi, h, h16);
    wprep_kernel<<<(3 * 4 * 6 * 64 * 8 + 255) / 256, 256, 0, stream>>>(Wz, Wr, Wh, wf_hi, wf_lo);
    count_rows_kernel<<<NODES / 4, 256, 0, stream>>>((const float4*)adj, cnt_in, edge_in,
                                                     cnt_out, edge_out);

    for (int step = 0; step < STEPS; ++step) {
        aggregate_kernel<<<NODES / 4, 256, 0, stream>>>(
            (const uint4*)h16, h, cnt_in, edge_in, cnt_out, edge_out, xs);
        gate_kernel<<<NODES / 16, 256, 0, stream>>>(xs, wf_hi, wf_lo, bz, br, bh, h, h16);
    }
    out_kernel<<<NODES * HD / 256, 256, 0, stream>>>(h, Wo, bo, out);
}